// Round 6
// baseline (311.655 us; speedup 1.0000x reference)
//
#include <hip/hip_runtime.h>
#include <hip/hip_bf16.h>

#define H 16
#define BB 2
#define SS 2048
#define DMODEL 1024
#define ROWS (BB * SS)   // 4096

typedef __attribute__((ext_vector_type(8))) short bf16x8;
typedef __attribute__((ext_vector_type(4))) float f32x4;

__device__ __forceinline__ short f2bf(float f) {
    union { float f; unsigned u; } v; v.f = f;
    unsigned r = v.u + 0x7fffu + ((v.u >> 16) & 1u);
    return (short)(r >> 16);
}

__device__ __forceinline__ void gload_lds16(const void* g, void* l) {
    __builtin_amdgcn_global_load_lds(
        (const __attribute__((address_space(1))) char*)g,
        (__attribute__((address_space(3))) char*)l, 16, 0, 0);
}

// fp32 -> bf16: q,k (4M each) and 4 weight matrices (1M each).
// Grid 6144 flat blocks x 256 thr; one bf16x8 per thread.
__global__ __launch_bounds__(256)
void cvt(const float* __restrict__ q, const float* __restrict__ k,
         const float* __restrict__ wq, const float* __restrict__ wk,
         const float* __restrict__ wv, const float* __restrict__ wo,
         short* __restrict__ Qb, short* __restrict__ Kb, short* __restrict__ Wb)
{
    const int bid = blockIdx.x;
    const float* s; short* d; int lb;
    if (bid < 2048)      { s = q; d = Qb; lb = bid; }
    else if (bid < 4096) { s = k; d = Kb; lb = bid - 2048; }
    else {
        const int w = (bid - 4096) >> 9;
        lb = (bid - 4096) & 511;
        s = (w == 0) ? wq : (w == 1) ? wk : (w == 2) ? wv : wo;
        d = Wb + (size_t)w * (DMODEL * DMODEL);
    }
    const int p = lb * 256 + threadIdx.x;
    const f32x4* sv = (const f32x4*)s;
    f32x4 a = sv[2 * p], c = sv[2 * p + 1];
    bf16x8 o;
    o[0] = f2bf(a[0]); o[1] = f2bf(a[1]); o[2] = f2bf(a[2]); o[3] = f2bf(a[3]);
    o[4] = f2bf(c[0]); o[5] = f2bf(c[1]); o[6] = f2bf(c[2]); o[7] = f2bf(c[3]);
    ((bf16x8*)d)[p] = o;
}

// Stage 128x64 bf16 tile via global_load_lds, chunk-XOR-swizzled source.
// LDS layout [128][64] shorts; LDS chunk c of row r holds global chunk c^(r&7).
__device__ __forceinline__ void stage_bf16_128(const short* __restrict__ src, int kt,
                                               char* lds, int wid, int lane)
{
    const int r0 = wid * 8 + (lane >> 3);
    const int ch = (lane & 7) ^ (lane >> 3);
#pragma unroll
    for (int i = 0; i < 4; i++)
        gload_lds16(&src[(size_t)(i * 32 + r0) * DMODEL + kt + ch * 8],
                    lds + i * 4096 + wid * 1024);
}

__device__ __forceinline__ void stage_bf16_64(const short* __restrict__ src, int kt,
                                              char* lds, int wid, int lane)
{
    const int r0 = wid * 8 + (lane >> 3);
    const int ch = (lane & 7) ^ (lane >> 3);
#pragma unroll
    for (int i = 0; i < 2; i++)
        gload_lds16(&src[(size_t)(i * 32 + r0) * DMODEL + kt + ch * 8],
                    lds + i * 4096 + wid * 1024);
}

// Fused Q/K/V projection. 768 blocks, XCD-chunked. 128x128 tile, BK=64,
// double-buffered LDS, one barrier per K-iter.
// op 0: Qh = (Qb @ Wq^T + bq)*0.125, head-major [B,H,S,64]
// op 1: Kh = (Kb @ Wk^T + bk),       head-major
// op 2: Vt = (Wv @ v^T + bv),        row-major [1024][4096] (B operand fp32)
__global__ __launch_bounds__(256, 2)
void qkv_proj(const short* __restrict__ Qb, const short* __restrict__ Kb,
              const float* __restrict__ vf,
              const short* __restrict__ Wq, const short* __restrict__ Wk,
              const short* __restrict__ Wv,
              const float* __restrict__ bq, const float* __restrict__ bk,
              const float* __restrict__ bv,
              short* __restrict__ Qh, short* __restrict__ Kh,
              short* __restrict__ Vt)
{
    __shared__ short As[2][128 * 64];
    __shared__ short Bs[2][128 * 64];

    const int fbid = blockIdx.x;
    const int vbid = (fbid & 7) * 96 + (fbid >> 3);   // XCD-chunked, bijective
    const int op   = vbid >> 8;
    const int tile = vbid & 255;
    const int t    = threadIdx.x;
    const int lane = t & 63;
    const int wid  = t >> 6;
    const int wm   = wid >> 1;
    const int wn   = wid & 1;
    const int l15  = lane & 15;
    const int l4   = lane >> 4;

    const short* Asrc; const short* Bsrc = nullptr; const float* bias;
    short* C; int m0, n0; float scale = 1.0f; bool regB = false;
    if (op == 0) {
        Asrc = Qb; Bsrc = Wq; bias = bq; C = Qh;
        m0 = (tile >> 3) * 128; n0 = (tile & 7) * 128; scale = 0.125f;
    } else if (op == 1) {
        Asrc = Kb; Bsrc = Wk; bias = bk; C = Kh;
        m0 = (tile >> 3) * 128; n0 = (tile & 7) * 128;
    } else {
        Asrc = Wv; bias = bv; C = Vt; regB = true;
        m0 = (tile >> 5) * 128; n0 = (tile & 31) * 128;
    }
    Asrc += (size_t)m0 * DMODEL;

    f32x4 acc[4][4];
#pragma unroll
    for (int i = 0; i < 4; i++)
#pragma unroll
        for (int j = 0; j < 4; j++) acc[i][j] = (f32x4)0.0f;

    const int brow = t >> 1, bhalf = t & 1;   // fp32 B staging geometry

    // prologue: stage tile 0 into buffer 0
    stage_bf16_128(Asrc, 0, (char*)As[0], wid, lane);
    if (!regB) {
        stage_bf16_128(Bsrc + (size_t)n0 * DMODEL, 0, (char*)Bs[0], wid, lane);
    } else {
        const f32x4* p = (const f32x4*)&vf[(size_t)(n0 + brow) * DMODEL + bhalf * 32];
        f32x4 br[8];
#pragma unroll
        for (int j = 0; j < 8; j++) br[j] = p[j];
#pragma unroll
        for (int c = 0; c < 4; c++) {
            f32x4 x = br[2 * c], y = br[2 * c + 1];
            bf16x8 w;
            w[0]=f2bf(x[0]); w[1]=f2bf(x[1]); w[2]=f2bf(x[2]); w[3]=f2bf(x[3]);
            w[4]=f2bf(y[0]); w[5]=f2bf(y[1]); w[6]=f2bf(y[2]); w[7]=f2bf(y[3]);
            *(bf16x8*)&Bs[0][brow * 64 + ((bhalf * 4 + c) ^ (brow & 7)) * 8] = w;
        }
    }
    __syncthreads();

    int cur = 0;
    for (int kt = 0; kt < DMODEL; kt += 64) {
        const int nxt = cur ^ 1;
        const bool pre = (kt + 64 < DMODEL);
        f32x4 br[8];
        if (pre) {
            stage_bf16_128(Asrc, kt + 64, (char*)As[nxt], wid, lane);
            if (!regB) {
                stage_bf16_128(Bsrc + (size_t)n0 * DMODEL, kt + 64, (char*)Bs[nxt], wid, lane);
            } else {
                const f32x4* p = (const f32x4*)&vf[(size_t)(n0 + brow) * DMODEL + kt + 64 + bhalf * 32];
#pragma unroll
                for (int j = 0; j < 8; j++) br[j] = p[j];
            }
        }

#pragma unroll
        for (int kk = 0; kk < 2; kk++) {
            bf16x8 a[4], b[4];
            const int ch = ((kk * 4 + l4) ^ (l15 & 7)) * 8;
#pragma unroll
            for (int i = 0; i < 4; i++)
                a[i] = *(const bf16x8*)&As[cur][(wm * 64 + i * 16 + l15) * 64 + ch];
#pragma unroll
            for (int j = 0; j < 4; j++)
                b[j] = *(const bf16x8*)&Bs[cur][(wn * 64 + j * 16 + l15) * 64 + ch];
#pragma unroll
            for (int i = 0; i < 4; i++)
#pragma unroll
                for (int j = 0; j < 4; j++)
                    acc[i][j] = __builtin_amdgcn_mfma_f32_16x16x32_bf16(a[i], b[j], acc[i][j], 0, 0, 0);
        }

        if (pre && regB) {
#pragma unroll
            for (int c = 0; c < 4; c++) {
                f32x4 x = br[2 * c], y = br[2 * c + 1];
                bf16x8 w;
                w[0]=f2bf(x[0]); w[1]=f2bf(x[1]); w[2]=f2bf(x[2]); w[3]=f2bf(x[3]);
                w[4]=f2bf(y[0]); w[5]=f2bf(y[1]); w[6]=f2bf(y[2]); w[7]=f2bf(y[3]);
                *(bf16x8*)&Bs[nxt][brow * 64 + ((bhalf * 4 + c) ^ (brow & 7)) * 8] = w;
            }
        }
        __syncthreads();
        cur = nxt;
    }

#pragma unroll
    for (int i = 0; i < 4; i++) {
        const int mbase = m0 + wm * 64 + i * 16 + l4 * 4;
#pragma unroll
        for (int j = 0; j < 4; j++) {
            const int n = n0 + wn * 64 + j * 16 + l15;
#pragma unroll
            for (int r = 0; r < 4; r++) {
                const int m = mbase + r;
                if (op < 2) {
                    float y = (acc[i][j][r] + bias[n]) * scale;
                    const int b_ = m >> 11, s_ = m & 2047;
                    const int h_ = n >> 6,  d_ = n & 63;
                    C[((((size_t)b_ * H + h_) * SS + s_) << 6) + d_] = f2bf(y);
                } else {
                    C[(size_t)m * ROWS + n] = f2bf(acc[i][j][r] + bias[m]);
                }
            }
        }
    }
}

// O-projection: OW[4096][1024] fp32 = Oc @ Wo^T + bo. 64x128 tiles, BK=64,
// dbuf, 512 blocks XCD-chunked.
__global__ __launch_bounds__(256, 2)
void oproj(const short* __restrict__ Oc, const short* __restrict__ Wo,
           const float* __restrict__ bo, float* __restrict__ out)
{
    __shared__ short As[2][64 * 64];
    __shared__ short Bs[2][128 * 64];

    const int fbid = blockIdx.x;
    const int vbid = (fbid & 7) * 64 + (fbid >> 3);
    const int m0   = (vbid >> 3) * 64;
    const int n0   = (vbid & 7) * 128;
    const int t    = threadIdx.x;
    const int lane = t & 63;
    const int wid  = t >> 6;
    const int wm   = wid >> 1;
    const int wn   = wid & 1;
    const int l15  = lane & 15;
    const int l4   = lane >> 4;

    f32x4 acc[2][4];
#pragma unroll
    for (int i = 0; i < 2; i++)
#pragma unroll
        for (int j = 0; j < 4; j++) acc[i][j] = (f32x4)0.0f;

    stage_bf16_64 (Oc + (size_t)m0 * DMODEL, 0, (char*)As[0], wid, lane);
    stage_bf16_128(Wo + (size_t)n0 * DMODEL, 0, (char*)Bs[0], wid, lane);
    __syncthreads();

    int cur = 0;
    for (int kt = 0; kt < DMODEL; kt += 64) {
        const int nxt = cur ^ 1;
        if (kt + 64 < DMODEL) {
            stage_bf16_64 (Oc + (size_t)m0 * DMODEL, kt + 64, (char*)As[nxt], wid, lane);
            stage_bf16_128(Wo + (size_t)n0 * DMODEL, kt + 64, (char*)Bs[nxt], wid, lane);
        }
#pragma unroll
        for (int kk = 0; kk < 2; kk++) {
            bf16x8 a[2], b[4];
            const int ch = ((kk * 4 + l4) ^ (l15 & 7)) * 8;
#pragma unroll
            for (int i = 0; i < 2; i++)
                a[i] = *(const bf16x8*)&As[cur][(wm * 32 + i * 16 + l15) * 64 + ch];
#pragma unroll
            for (int j = 0; j < 4; j++)
                b[j] = *(const bf16x8*)&Bs[cur][(wn * 64 + j * 16 + l15) * 64 + ch];
#pragma unroll
            for (int i = 0; i < 2; i++)
#pragma unroll
                for (int j = 0; j < 4; j++)
                    acc[i][j] = __builtin_amdgcn_mfma_f32_16x16x32_bf16(a[i], b[j], acc[i][j], 0, 0, 0);
        }
        __syncthreads();
        cur = nxt;
    }

#pragma unroll
    for (int i = 0; i < 2; i++) {
        const int mbase = m0 + wm * 32 + i * 16 + l4 * 4;
#pragma unroll
        for (int j = 0; j < 4; j++) {
            const int n = n0 + wn * 64 + j * 16 + l15;
#pragma unroll
            for (int r = 0; r < 4; r++)
                out[(size_t)(mbase + r) * DMODEL + n] = acc[i][j][r] + bo[n];
        }
    }
}

// Flash attention, causal, paired q-tiles, double-buffered K/V, 1 barrier/iter.
__global__ __launch_bounds__(256, 2)
void attn_fwd(const short* __restrict__ Qh, const short* __restrict__ Kh,
              const short* __restrict__ Vt, short* __restrict__ Oc)
{
    __shared__ short Ks[2][64][64];
    __shared__ short Vs[2][64][64];
    __shared__ short Ps[4][16][72];

    const int t    = threadIdx.x;
    const int lane = t & 63;
    const int wid  = t >> 6;
    const int fbid = blockIdx.x;
    const int vbid = (fbid & 7) * 64 + (fbid >> 3);
    const int bh   = vbid >> 4;
    const int qp   = vbid & 15;
    const int b    = bh >> 4;
    const int h    = bh & 15;
    const int l15  = lane & 15;
    const int l4   = lane >> 4;

    const int srow = wid * 8 + (lane >> 3);
    const int sch  = lane & 7;
    const int ldsoff = wid * 1024;

    auto stage = [&](int buf, int kvt) {
#pragma unroll
        for (int i = 0; i < 2; i++) {
            const int row = i * 32 + srow;
            const int chg = sch ^ (row & 7);
            gload_lds16(&Kh[((size_t)bh * SS + kvt * 64 + row) * 64 + chg * 8],
                        (char*)Ks + buf * 8192 + ldsoff + i * 4096);
            gload_lds16(&Vt[((size_t)(h * 64 + row)) * ROWS + b * SS + kvt * 64 + chg * 8],
                        (char*)Vs + buf * 8192 + ldsoff + i * 4096);
        }
    };

    for (int half = 0; half < 2; ++half) {
        const int qt = half ? (31 - qp) : qp;

        bf16x8 qa[2];
        {
            const int qrow = qt * 64 + wid * 16 + l15;
            const size_t base = ((size_t)bh * SS + qrow) * 64;
            qa[0] = *(const bf16x8*)&Qh[base + l4 * 8];
            qa[1] = *(const bf16x8*)&Qh[base + 32 + l4 * 8];
        }

        f32x4 accO[4];
#pragma unroll
        for (int i = 0; i < 4; i++) accO[i] = (f32x4)0.f;
        float mrun[4], lrun[4];
#pragma unroll
        for (int r = 0; r < 4; r++) { mrun[r] = -1e30f; lrun[r] = 0.f; }

        stage(0, 0);
        __syncthreads();

        int cur = 0;
        for (int kvt = 0; kvt <= qt; ++kvt) {
            if (kvt < qt) stage(cur ^ 1, kvt + 1);

            f32x4 sc[4];
#pragma unroll
            for (int i = 0; i < 4; i++) sc[i] = (f32x4)0.f;
            __builtin_amdgcn_s_setprio(1);
#pragma unroll
            for (int kk = 0; kk < 2; kk++) {
#pragma unroll
                for (int fn = 0; fn < 4; fn++) {
                    const int ch = (kk * 4 + l4) ^ (l15 & 7);
                    bf16x8 kb = *(const bf16x8*)&Ks[cur][fn * 16 + l15][ch * 8];
                    sc[fn] = __builtin_amdgcn_mfma_f32_16x16x32_bf16(qa[kk], kb, sc[fn], 0, 0, 0);
                }
            }
            __builtin_amdgcn_s_setprio(0);

            if (kvt == qt) {
#pragma unroll
                for (int fn = 0; fn < 4; fn++) {
                    const int kvg = fn * 16 + l15;
#pragma unroll
                    for (int r = 0; r < 4; r++) {
                        const int qg = wid * 16 + l4 * 4 + r;
                        if (kvg > qg) sc[fn][r] = -1e30f;
                    }
                }
            }

            float es[4], rs[4];
#pragma unroll
            for (int r = 0; r < 4; r++) {
                float v = fmaxf(fmaxf(sc[0][r], sc[1][r]), fmaxf(sc[2][r], sc[3][r]));
                v = fmaxf(v, __shfl_xor(v, 1));
                v = fmaxf(v, __shfl_xor(v, 2));
                v = fmaxf(v, __shfl_xor(v, 4));
                v = fmaxf(v, __shfl_xor(v, 8));
                const float mn = fmaxf(mrun[r], v);
                es[r] = __expf(mrun[r] - mn);
                mrun[r] = mn;
                rs[r] = 0.f;
            }
#pragma unroll
            for (int fn = 0; fn < 4; fn++)
#pragma unroll
                for (int r = 0; r < 4; r++) {
                    const float p = __expf(sc[fn][r] - mrun[r]);
                    sc[fn][r] = p;
                    rs[r] += p;
                }
#pragma unroll
            for (int r = 0; r < 4; r++) {
                float v = rs[r];
                v += __shfl_xor(v, 1);
                v += __shfl_xor(v, 2);
                v += __shfl_xor(v, 4);
                v += __shfl_xor(v, 8);
                lrun[r] = lrun[r] * es[r] + v;
            }
#pragma unroll
            for (int i = 0; i < 4; i++)
#pragma unroll
                for (int r = 0; r < 4; r++) accO[i][r] *= es[r];

#pragma unroll
            for (int fn = 0; fn < 4; fn++)
#pragma unroll
                for (int r = 0; r < 4; r++)
                    Ps[wid][l4 * 4 + r][fn * 16 + l15] = f2bf(sc[fn][r]);

            __builtin_amdgcn_s_setprio(1);
#pragma unroll
            for (int kk = 0; kk < 2; kk++) {
                bf16x8 pa = *(const bf16x8*)&Ps[wid][l15][kk * 32 + l4 * 8];
#pragma unroll
                for (int fd = 0; fd < 4; fd++) {
                    const int ch = (kk * 4 + l4) ^ (l15 & 7);
                    bf16x8 vb = *(const bf16x8*)&Vs[cur][fd * 16 + l15][ch * 8];
                    accO[fd] = __builtin_amdgcn_mfma_f32_16x16x32_bf16(pa, vb, accO[fd], 0, 0, 0);
                }
            }
            __builtin_amdgcn_s_setprio(0);

            __syncthreads();
            cur ^= 1;
        }

        float inv[4];
#pragma unroll
        for (int r = 0; r < 4; r++) inv[r] = 1.0f / lrun[r];
#pragma unroll
        for (int fd = 0; fd < 4; fd++)
#pragma unroll
            for (int r = 0; r < 4; r++) {
                const int q = qt * 64 + wid * 16 + l4 * 4 + r;
                const size_t idx = ((size_t)b * SS + q) * DMODEL + h * 64 + fd * 16 + l15;
                Oc[idx] = f2bf(accO[fd][r] * inv[r]);
            }
    }
}

extern "C" void kernel_launch(void* const* d_in, const int* in_sizes, int n_in,
                              void* d_out, int out_size, void* d_ws, size_t ws_size,
                              hipStream_t stream) {
    const float* q   = (const float*)d_in[0];
    const float* k   = (const float*)d_in[1];
    const float* v   = (const float*)d_in[2];
    const float* w_q = (const float*)d_in[4];
    const float* b_q = (const float*)d_in[5];
    const float* w_k = (const float*)d_in[6];
    const float* b_k = (const float*)d_in[7];
    const float* w_v = (const float*)d_in[8];
    const float* b_v = (const float*)d_in[9];
    const float* w_o = (const float*)d_in[10];
    const float* b_o = (const float*)d_in[11];

    const size_t T = (size_t)ROWS * DMODEL;   // 4M elements
    const size_t W = (size_t)DMODEL * DMODEL; // 1M elements
    // ws (32 MB): [Qh 8][Kh 8][Vt 8][Wq|Wk|Wv|Wo bf16 8]; oproj fp32 out reuses [0:16]
    short* Qh  = (short*)d_ws;
    short* Kh  = Qh + T;
    short* Vt  = Kh + T;
    short* Wb  = Vt + T;
    short* Wq16 = Wb, *Wk16 = Wb + W, *Wv16 = Wb + 2 * W, *Wo16 = Wb + 3 * W;
    // d_out (16 MB) as scratch: [Qb 8][Kb 8]; later Oc bf16 over Qb region
    short* Qb  = (short*)d_out;
    short* Kb  = Qb + T;
    short* Oc  = (short*)d_out;
    float* OW  = (float*)d_ws;                // oproj fp32 result (over dead Qh/Kh)

    dim3 blk(256);
    cvt<<<dim3(6144), blk, 0, stream>>>(q, k, w_q, w_k, w_v, w_o, Qb, Kb, Wb);
    qkv_proj<<<dim3(768), blk, 0, stream>>>(Qb, Kb, v, Wq16, Wk16, Wv16,
                                            b_q, b_k, b_v, Qh, Kh, Vt);
    attn_fwd<<<dim3(512), blk, 0, stream>>>(Qh, Kh, Vt, Oc);
    oproj<<<dim3(512), blk, 0, stream>>>(Oc, Wo16, b_o, OW);
    hipMemcpyAsync(d_out, d_ws, (size_t)ROWS * DMODEL * sizeof(float),
                   hipMemcpyDeviceToDevice, stream);
}

// Round 7
// 282.694 us; speedup vs baseline: 1.1024x; 1.1024x over previous
//
#include <hip/hip_runtime.h>
#include <hip/hip_bf16.h>

#define H 16
#define BB 2
#define SS 2048
#define DMODEL 1024
#define ROWS (BB * SS)   // 4096

typedef __attribute__((ext_vector_type(8))) short bf16x8;
typedef __attribute__((ext_vector_type(4))) float f32x4;

__device__ __forceinline__ short f2bf(float f) {
    union { float f; unsigned u; } v; v.f = f;
    unsigned r = v.u + 0x7fffu + ((v.u >> 16) & 1u);
    return (short)(r >> 16);
}

__device__ __forceinline__ void gload_lds16(const void* g, void* l) {
    __builtin_amdgcn_global_load_lds(
        (const __attribute__((address_space(1))) char*)g,
        (__attribute__((address_space(3))) char*)l, 16, 0, 0);
}

// fp32 -> bf16: q,k (4M each) and 4 weight matrices (1M each).
__global__ __launch_bounds__(256)
void cvt(const float* __restrict__ q, const float* __restrict__ k,
         const float* __restrict__ wq, const float* __restrict__ wk,
         const float* __restrict__ wv, const float* __restrict__ wo,
         short* __restrict__ Qb, short* __restrict__ Kb, short* __restrict__ Wb)
{
    const int bid = blockIdx.x;
    const float* s; short* d; int lb;
    if (bid < 2048)      { s = q; d = Qb; lb = bid; }
    else if (bid < 4096) { s = k; d = Kb; lb = bid - 2048; }
    else {
        const int w = (bid - 4096) >> 9;
        lb = (bid - 4096) & 511;
        s = (w == 0) ? wq : (w == 1) ? wk : (w == 2) ? wv : wo;
        d = Wb + (size_t)w * (DMODEL * DMODEL);
    }
    const int p = lb * 256 + threadIdx.x;
    const f32x4* sv = (const f32x4*)s;
    f32x4 a = sv[2 * p], c = sv[2 * p + 1];
    bf16x8 o;
    o[0] = f2bf(a[0]); o[1] = f2bf(a[1]); o[2] = f2bf(a[2]); o[3] = f2bf(a[3]);
    o[4] = f2bf(c[0]); o[5] = f2bf(c[1]); o[6] = f2bf(c[2]); o[7] = f2bf(c[3]);
    ((bf16x8*)d)[p] = o;
}

// BK=32 stagers. LDS tile [R][32] shorts (64B rows); physical chunk of row r,
// logical chunk c is c ^ ((r>>1)&3)  -> conflict-free b128 frag reads.
// gload_lds writes linearly; swizzle applied on the global source address.
__device__ __forceinline__ void stage32_128(const short* __restrict__ src, int kt,
                                            char* lds, int wid, int lane)
{
#pragma unroll
    for (int i = 0; i < 2; i++) {
        const int blk = wid * 2 + i;
        const int row = blk * 16 + (lane >> 2);
        const int g   = (lane & 3) ^ ((lane >> 3) & 3);
        gload_lds16(&src[(size_t)row * DMODEL + kt + g * 8], lds + blk * 1024);
    }
}

__device__ __forceinline__ void stage32_64(const short* __restrict__ src, int kt,
                                           char* lds, int wid, int lane)
{
    const int row = wid * 16 + (lane >> 2);
    const int g   = (lane & 3) ^ ((lane >> 3) & 3);
    gload_lds16(&src[(size_t)row * DMODEL + kt + g * 8], lds + wid * 1024);
}

// Fused Q/K/V projection. 768 blocks XCD-chunked, 128x128 tile, BK=32,
// double-buffered LDS (32 KB), one barrier per K-iter, 3 blocks/CU.
// op 0: Qh = (Qb @ Wq^T + bq)*0.125, head-major [B,H,S,64]
// op 1: Kh = (Kb @ Wk^T + bk),       head-major
// op 2: Vt = (Wv @ v^T + bv),        row-major [1024][4096] (B = v fp32, reg-staged)
__global__ __launch_bounds__(256, 3)
void qkv_proj(const short* __restrict__ Qb, const short* __restrict__ Kb,
              const float* __restrict__ vf,
              const short* __restrict__ Wq, const short* __restrict__ Wk,
              const short* __restrict__ Wv,
              const float* __restrict__ bq, const float* __restrict__ bk,
              const float* __restrict__ bv,
              short* __restrict__ Qh, short* __restrict__ Kh,
              short* __restrict__ Vt)
{
    __shared__ short As[2][128 * 32];
    __shared__ short Bs[2][128 * 32];

    const int fbid = blockIdx.x;
    const int vbid = (fbid & 7) * 96 + (fbid >> 3);   // XCD-chunked, bijective
    const int op   = vbid >> 8;
    const int tile = vbid & 255;
    const int t    = threadIdx.x;
    const int lane = t & 63;
    const int wid  = t >> 6;
    const int wm   = wid >> 1;
    const int wn   = wid & 1;
    const int l15  = lane & 15;
    const int l4   = lane >> 4;

    const short* Asrc; const short* Bsrc = nullptr; const float* bias;
    short* C; int m0, n0; float scale = 1.0f; bool regB = false;
    if (op == 0) {
        Asrc = Qb; Bsrc = Wq; bias = bq; C = Qh;
        m0 = (tile >> 3) * 128; n0 = (tile & 7) * 128; scale = 0.125f;
    } else if (op == 1) {
        Asrc = Kb; Bsrc = Wk; bias = bk; C = Kh;
        m0 = (tile >> 3) * 128; n0 = (tile & 7) * 128;
    } else {
        // m-inner tile order: 8 consecutive blocks share one v-panel (L2 reuse)
        Asrc = Wv; bias = bv; C = Vt; regB = true;
        m0 = (tile & 7) * 128; n0 = (tile >> 3) * 128;
    }
    Asrc += (size_t)m0 * DMODEL;

    f32x4 acc[4][4];
#pragma unroll
    for (int i = 0; i < 4; i++)
#pragma unroll
        for (int j = 0; j < 4; j++) acc[i][j] = (f32x4)0.0f;

    const int brow = t >> 1, bh2 = t & 1;             // fp32 B staging geometry
    const int ch = (l4 ^ ((l15 >> 1) & 3)) * 8;       // swizzled frag-read chunk

    auto writeBrow = [&](int buf, const f32x4* br) {
#pragma unroll
        for (int j = 0; j < 2; j++) {
            f32x4 x = br[2 * j], y = br[2 * j + 1];
            bf16x8 w;
            w[0]=f2bf(x[0]); w[1]=f2bf(x[1]); w[2]=f2bf(x[2]); w[3]=f2bf(x[3]);
            w[4]=f2bf(y[0]); w[5]=f2bf(y[1]); w[6]=f2bf(y[2]); w[7]=f2bf(y[3]);
            const int cp = (bh2 * 2 + j) ^ ((brow >> 1) & 3);
            *(bf16x8*)&Bs[buf][brow * 32 + cp * 8] = w;
        }
    };

    // prologue: tile 0 into buffer 0
    stage32_128(Asrc, 0, (char*)As[0], wid, lane);
    if (!regB) {
        stage32_128(Bsrc + (size_t)n0 * DMODEL, 0, (char*)Bs[0], wid, lane);
    } else {
        f32x4 br[4];
        const f32x4* p = (const f32x4*)&vf[(size_t)(n0 + brow) * DMODEL + bh2 * 16];
#pragma unroll
        for (int j = 0; j < 4; j++) br[j] = p[j];
        writeBrow(0, br);
    }
    __syncthreads();

    int cur = 0;
    for (int kt = 0; kt < DMODEL; kt += 32) {
        const int nxt = cur ^ 1;
        const bool pre = (kt + 32 < DMODEL);
        f32x4 br[4];
        if (pre) {
            stage32_128(Asrc, kt + 32, (char*)As[nxt], wid, lane);
            if (!regB) {
                stage32_128(Bsrc + (size_t)n0 * DMODEL, kt + 32, (char*)Bs[nxt], wid, lane);
            } else {
                const f32x4* p = (const f32x4*)&vf[(size_t)(n0 + brow) * DMODEL + kt + 32 + bh2 * 16];
#pragma unroll
                for (int j = 0; j < 4; j++) br[j] = p[j];
            }
        }

        bf16x8 a[4], b[4];
#pragma unroll
        for (int i = 0; i < 4; i++)
            a[i] = *(const bf16x8*)&As[cur][(wm * 64 + i * 16 + l15) * 32 + ch];
#pragma unroll
        for (int j = 0; j < 4; j++)
            b[j] = *(const bf16x8*)&Bs[cur][(wn * 64 + j * 16 + l15) * 32 + ch];
#pragma unroll
        for (int i = 0; i < 4; i++)
#pragma unroll
            for (int j = 0; j < 4; j++)
                acc[i][j] = __builtin_amdgcn_mfma_f32_16x16x32_bf16(a[i], b[j], acc[i][j], 0, 0, 0);

        if (pre && regB) writeBrow(nxt, br);
        __syncthreads();
        cur = nxt;
    }

#pragma unroll
    for (int i = 0; i < 4; i++) {
        const int mbase = m0 + wm * 64 + i * 16 + l4 * 4;
#pragma unroll
        for (int j = 0; j < 4; j++) {
            const int n = n0 + wn * 64 + j * 16 + l15;
#pragma unroll
            for (int r = 0; r < 4; r++) {
                const int m = mbase + r;
                if (op < 2) {
                    float y = (acc[i][j][r] + bias[n]) * scale;
                    const int b_ = m >> 11, s_ = m & 2047;
                    const int h_ = n >> 6,  d_ = n & 63;
                    C[((((size_t)b_ * H + h_) * SS + s_) << 6) + d_] = f2bf(y);
                } else {
                    C[(size_t)m * ROWS + n] = f2bf(acc[i][j][r] + bias[m]);
                }
            }
        }
    }
}

// O-projection: OW[4096][1024] fp32 = Oc @ Wo^T + bo. 64x128 tiles, BK=32,
// dbuf (24 KB LDS), 512 blocks XCD-chunked, 3 blocks/CU.
__global__ __launch_bounds__(256, 3)
void oproj(const short* __restrict__ Oc, const short* __restrict__ Wo,
           const float* __restrict__ bo, float* __restrict__ out)
{
    __shared__ short As[2][64 * 32];
    __shared__ short Bs[2][128 * 32];

    const int fbid = blockIdx.x;
    const int vbid = (fbid & 7) * 64 + (fbid >> 3);
    const int m0   = (vbid >> 3) * 64;
    const int n0   = (vbid & 7) * 128;
    const int t    = threadIdx.x;
    const int lane = t & 63;
    const int wid  = t >> 6;
    const int wm   = wid >> 1;
    const int wn   = wid & 1;
    const int l15  = lane & 15;
    const int l4   = lane >> 4;
    const int ch   = (l4 ^ ((l15 >> 1) & 3)) * 8;

    f32x4 acc[2][4];
#pragma unroll
    for (int i = 0; i < 2; i++)
#pragma unroll
        for (int j = 0; j < 4; j++) acc[i][j] = (f32x4)0.0f;

    stage32_64 (Oc + (size_t)m0 * DMODEL, 0, (char*)As[0], wid, lane);
    stage32_128(Wo + (size_t)n0 * DMODEL, 0, (char*)Bs[0], wid, lane);
    __syncthreads();

    int cur = 0;
    for (int kt = 0; kt < DMODEL; kt += 32) {
        const int nxt = cur ^ 1;
        if (kt + 32 < DMODEL) {
            stage32_64 (Oc + (size_t)m0 * DMODEL, kt + 32, (char*)As[nxt], wid, lane);
            stage32_128(Wo + (size_t)n0 * DMODEL, kt + 32, (char*)Bs[nxt], wid, lane);
        }
        bf16x8 a[2], b[4];
#pragma unroll
        for (int i = 0; i < 2; i++)
            a[i] = *(const bf16x8*)&As[cur][(wm * 32 + i * 16 + l15) * 32 + ch];
#pragma unroll
        for (int j = 0; j < 4; j++)
            b[j] = *(const bf16x8*)&Bs[cur][(wn * 64 + j * 16 + l15) * 32 + ch];
#pragma unroll
        for (int i = 0; i < 2; i++)
#pragma unroll
            for (int j = 0; j < 4; j++)
                acc[i][j] = __builtin_amdgcn_mfma_f32_16x16x32_bf16(a[i], b[j], acc[i][j], 0, 0, 0);
        __syncthreads();
        cur = nxt;
    }

#pragma unroll
    for (int i = 0; i < 2; i++) {
        const int mbase = m0 + wm * 32 + i * 16 + l4 * 4;
#pragma unroll
        for (int j = 0; j < 4; j++) {
            const int n = n0 + wn * 64 + j * 16 + l15;
#pragma unroll
            for (int r = 0; r < 4; r++)
                out[(size_t)(mbase + r) * DMODEL + n] = acc[i][j][r] + bo[n];
        }
    }
}

// Flash attention, causal, paired q-tiles, double-buffered K/V, 1 barrier/iter.
__global__ __launch_bounds__(256, 2)
void attn_fwd(const short* __restrict__ Qh, const short* __restrict__ Kh,
              const short* __restrict__ Vt, short* __restrict__ Oc)
{
    __shared__ short Ks[2][64][64];
    __shared__ short Vs[2][64][64];
    __shared__ short Ps[4][16][72];

    const int t    = threadIdx.x;
    const int lane = t & 63;
    const int wid  = t >> 6;
    const int fbid = blockIdx.x;
    const int vbid = (fbid & 7) * 64 + (fbid >> 3);
    const int bh   = vbid >> 4;
    const int qp   = vbid & 15;
    const int b    = bh >> 4;
    const int h    = bh & 15;
    const int l15  = lane & 15;
    const int l4   = lane >> 4;

    const int srow = wid * 8 + (lane >> 3);
    const int sch  = lane & 7;
    const int ldsoff = wid * 1024;

    auto stage = [&](int buf, int kvt) {
#pragma unroll
        for (int i = 0; i < 2; i++) {
            const int row = i * 32 + srow;
            const int chg = sch ^ (row & 7);
            gload_lds16(&Kh[((size_t)bh * SS + kvt * 64 + row) * 64 + chg * 8],
                        (char*)Ks + buf * 8192 + ldsoff + i * 4096);
            gload_lds16(&Vt[((size_t)(h * 64 + row)) * ROWS + b * SS + kvt * 64 + chg * 8],
                        (char*)Vs + buf * 8192 + ldsoff + i * 4096);
        }
    };

    for (int half = 0; half < 2; ++half) {
        const int qt = half ? (31 - qp) : qp;

        bf16x8 qa[2];
        {
            const int qrow = qt * 64 + wid * 16 + l15;
            const size_t base = ((size_t)bh * SS + qrow) * 64;
            qa[0] = *(const bf16x8*)&Qh[base + l4 * 8];
            qa[1] = *(const bf16x8*)&Qh[base + 32 + l4 * 8];
        }

        f32x4 accO[4];
#pragma unroll
        for (int i = 0; i < 4; i++) accO[i] = (f32x4)0.f;
        float mrun[4], lrun[4];
#pragma unroll
        for (int r = 0; r < 4; r++) { mrun[r] = -1e30f; lrun[r] = 0.f; }

        stage(0, 0);
        __syncthreads();

        int cur = 0;
        for (int kvt = 0; kvt <= qt; ++kvt) {
            if (kvt < qt) stage(cur ^ 1, kvt + 1);

            f32x4 sc[4];
#pragma unroll
            for (int i = 0; i < 4; i++) sc[i] = (f32x4)0.f;
            __builtin_amdgcn_s_setprio(1);
#pragma unroll
            for (int kk = 0; kk < 2; kk++) {
#pragma unroll
                for (int fn = 0; fn < 4; fn++) {
                    const int chk = (kk * 4 + l4) ^ (l15 & 7);
                    bf16x8 kb = *(const bf16x8*)&Ks[cur][fn * 16 + l15][chk * 8];
                    sc[fn] = __builtin_amdgcn_mfma_f32_16x16x32_bf16(qa[kk], kb, sc[fn], 0, 0, 0);
                }
            }
            __builtin_amdgcn_s_setprio(0);

            if (kvt == qt) {
#pragma unroll
                for (int fn = 0; fn < 4; fn++) {
                    const int kvg = fn * 16 + l15;
#pragma unroll
                    for (int r = 0; r < 4; r++) {
                        const int qg = wid * 16 + l4 * 4 + r;
                        if (kvg > qg) sc[fn][r] = -1e30f;
                    }
                }
            }

            float es[4], rs[4];
#pragma unroll
            for (int r = 0; r < 4; r++) {
                float v = fmaxf(fmaxf(sc[0][r], sc[1][r]), fmaxf(sc[2][r], sc[3][r]));
                v = fmaxf(v, __shfl_xor(v, 1));
                v = fmaxf(v, __shfl_xor(v, 2));
                v = fmaxf(v, __shfl_xor(v, 4));
                v = fmaxf(v, __shfl_xor(v, 8));
                const float mn = fmaxf(mrun[r], v);
                es[r] = __expf(mrun[r] - mn);
                mrun[r] = mn;
                rs[r] = 0.f;
            }
#pragma unroll
            for (int fn = 0; fn < 4; fn++)
#pragma unroll
                for (int r = 0; r < 4; r++) {
                    const float p = __expf(sc[fn][r] - mrun[r]);
                    sc[fn][r] = p;
                    rs[r] += p;
                }
#pragma unroll
            for (int r = 0; r < 4; r++) {
                float v = rs[r];
                v += __shfl_xor(v, 1);
                v += __shfl_xor(v, 2);
                v += __shfl_xor(v, 4);
                v += __shfl_xor(v, 8);
                lrun[r] = lrun[r] * es[r] + v;
            }
#pragma unroll
            for (int i = 0; i < 4; i++)
#pragma unroll
                for (int r = 0; r < 4; r++) accO[i][r] *= es[r];

#pragma unroll
            for (int fn = 0; fn < 4; fn++)
#pragma unroll
                for (int r = 0; r < 4; r++)
                    Ps[wid][l4 * 4 + r][fn * 16 + l15] = f2bf(sc[fn][r]);

            __builtin_amdgcn_s_setprio(1);
#pragma unroll
            for (int kk = 0; kk < 2; kk++) {
                bf16x8 pa = *(const bf16x8*)&Ps[wid][l15][kk * 32 + l4 * 8];
#pragma unroll
                for (int fd = 0; fd < 4; fd++) {
                    const int chk = (kk * 4 + l4) ^ (l15 & 7);
                    bf16x8 vb = *(const bf16x8*)&Vs[cur][fd * 16 + l15][chk * 8];
                    accO[fd] = __builtin_amdgcn_mfma_f32_16x16x32_bf16(pa, vb, accO[fd], 0, 0, 0);
                }
            }
            __builtin_amdgcn_s_setprio(0);

            __syncthreads();
            cur ^= 1;
        }

        float inv[4];
#pragma unroll
        for (int r = 0; r < 4; r++) inv[r] = 1.0f / lrun[r];
#pragma unroll
        for (int fd = 0; fd < 4; fd++)
#pragma unroll
            for (int r = 0; r < 4; r++) {
                const int q = qt * 64 + wid * 16 + l4 * 4 + r;
                const size_t idx = ((size_t)b * SS + q) * DMODEL + h * 64 + fd * 16 + l15;
                Oc[idx] = f2bf(accO[fd][r] * inv[r]);
            }
    }
}

extern "C" void kernel_launch(void* const* d_in, const int* in_sizes, int n_in,
                              void* d_out, int out_size, void* d_ws, size_t ws_size,
                              hipStream_t stream) {
    const float* q   = (const float*)d_in[0];
    const float* k   = (const float*)d_in[1];
    const float* v   = (const float*)d_in[2];
    const float* w_q = (const float*)d_in[4];
    const float* b_q = (const float*)d_in[5];
    const float* w_k = (const float*)d_in[6];
    const float* b_k = (const float*)d_in[7];
    const float* w_v = (const float*)d_in[8];
    const float* b_v = (const float*)d_in[9];
    const float* w_o = (const float*)d_in[10];
    const float* b_o = (const float*)d_in[11];

    const size_t T = (size_t)ROWS * DMODEL;   // 4M elements
    const size_t W = (size_t)DMODEL * DMODEL; // 1M elements
    short* Qh  = (short*)d_ws;
    short* Kh  = Qh + T;
    short* Vt  = Kh + T;
    short* Wb  = Vt + T;
    short* Wq16 = Wb, *Wk16 = Wb + W, *Wv16 = Wb + 2 * W, *Wo16 = Wb + 3 * W;
    short* Qb  = (short*)d_out;
    short* Kb  = Qb + T;
    short* Oc  = (short*)d_out;
    float* OW  = (float*)d_ws;                // oproj fp32 result (over dead Qh/Kh)

    dim3 blk(256);
    cvt<<<dim3(6144), blk, 0, stream>>>(q, k, w_q, w_k, w_v, w_o, Qb, Kb, Wb);
    qkv_proj<<<dim3(768), blk, 0, stream>>>(Qb, Kb, v, Wq16, Wk16, Wv16,
                                            b_q, b_k, b_v, Qh, Kh, Vt);
    attn_fwd<<<dim3(512), blk, 0, stream>>>(Qh, Kh, Vt, Oc);
    oproj<<<dim3(512), blk, 0, stream>>>(Oc, Wo16, b_o, OW);
    hipMemcpyAsync(d_out, d_ws, (size_t)ROWS * DMODEL * sizeof(float),
                   hipMemcpyDeviceToDevice, stream);
}

// Round 8
// 262.294 us; speedup vs baseline: 1.1882x; 1.0778x over previous
//
#include <hip/hip_runtime.h>
#include <hip/hip_bf16.h>

#define H 16
#define BB 2
#define SS 2048
#define DMODEL 1024
#define ROWS (BB * SS)   // 4096

typedef __attribute__((ext_vector_type(8))) short bf16x8;
typedef __attribute__((ext_vector_type(4))) short short4v;
typedef __attribute__((ext_vector_type(4))) float f32x4;

__device__ __forceinline__ short f2bf(float f) {
    union { float f; unsigned u; } v; v.f = f;
    unsigned r = v.u + 0x7fffu + ((v.u >> 16) & 1u);
    return (short)(r >> 16);
}

__device__ __forceinline__ void gload_lds16(const void* g, void* l) {
    __builtin_amdgcn_global_load_lds(
        (const __attribute__((address_space(1))) char*)g,
        (__attribute__((address_space(3))) char*)l, 16, 0, 0);
}

// fp32 -> bf16: q,k (4M each) and 4 weight matrices (1M each).
__global__ __launch_bounds__(256)
void cvt(const float* __restrict__ q, const float* __restrict__ k,
         const float* __restrict__ wq, const float* __restrict__ wk,
         const float* __restrict__ wv, const float* __restrict__ wo,
         short* __restrict__ Qb, short* __restrict__ Kb, short* __restrict__ Wb)
{
    const int bid = blockIdx.x;
    const float* s; short* d; int lb;
    if (bid < 2048)      { s = q; d = Qb; lb = bid; }
    else if (bid < 4096) { s = k; d = Kb; lb = bid - 2048; }
    else {
        const int w = (bid - 4096) >> 9;
        lb = (bid - 4096) & 511;
        s = (w == 0) ? wq : (w == 1) ? wk : (w == 2) ? wv : wo;
        d = Wb + (size_t)w * (DMODEL * DMODEL);
    }
    const int p = lb * 256 + threadIdx.x;
    const f32x4* sv = (const f32x4*)s;
    f32x4 a = sv[2 * p], c = sv[2 * p + 1];
    bf16x8 o;
    o[0] = f2bf(a[0]); o[1] = f2bf(a[1]); o[2] = f2bf(a[2]); o[3] = f2bf(a[3]);
    o[4] = f2bf(c[0]); o[5] = f2bf(c[1]); o[6] = f2bf(c[2]); o[7] = f2bf(c[3]);
    ((bf16x8*)d)[p] = o;
}

// BK=32 stagers. LDS tile [R][32] shorts (64B rows); physical chunk of row r,
// logical chunk c is c ^ ((r>>1)&3)  -> conflict-free b128 frag reads.
__device__ __forceinline__ void stage32_128(const short* __restrict__ src, int kt,
                                            char* lds, int wid, int lane)
{
#pragma unroll
    for (int i = 0; i < 2; i++) {
        const int blk = wid * 2 + i;
        const int row = blk * 16 + (lane >> 2);
        const int g   = (lane & 3) ^ ((lane >> 3) & 3);
        gload_lds16(&src[(size_t)row * DMODEL + kt + g * 8], lds + blk * 1024);
    }
}

__device__ __forceinline__ void stage32_64(const short* __restrict__ src, int kt,
                                           char* lds, int wid, int lane)
{
    const int row = wid * 16 + (lane >> 2);
    const int g   = (lane & 3) ^ ((lane >> 3) & 3);
    gload_lds16(&src[(size_t)row * DMODEL + kt + g * 8], lds + wid * 1024);
}

// Fused Q/K/V projection. 768 blocks XCD-chunked, 128x128 tile, BK=32,
// double-buffered LDS (32 KB), one barrier per K-iter, 3 blocks/CU.
__global__ __launch_bounds__(256, 3)
void qkv_proj(const short* __restrict__ Qb, const short* __restrict__ Kb,
              const float* __restrict__ vf,
              const short* __restrict__ Wq, const short* __restrict__ Wk,
              const short* __restrict__ Wv,
              const float* __restrict__ bq, const float* __restrict__ bk,
              const float* __restrict__ bv,
              short* __restrict__ Qh, short* __restrict__ Kh,
              short* __restrict__ Vt)
{
    __shared__ short As[2][128 * 32];
    __shared__ short Bs[2][128 * 32];

    const int fbid = blockIdx.x;
    const int vbid = (fbid & 7) * 96 + (fbid >> 3);   // XCD-chunked, bijective
    const int op   = vbid >> 8;
    const int tile = vbid & 255;
    const int t    = threadIdx.x;
    const int lane = t & 63;
    const int wid  = t >> 6;
    const int wm   = wid >> 1;
    const int wn   = wid & 1;
    const int l15  = lane & 15;
    const int l4   = lane >> 4;

    const short* Asrc; const short* Bsrc = nullptr; const float* bias;
    short* C; int m0, n0; float scale = 1.0f; bool regB = false;
    if (op == 0) {
        Asrc = Qb; Bsrc = Wq; bias = bq; C = Qh;
        m0 = (tile >> 3) * 128; n0 = (tile & 7) * 128; scale = 0.125f;
    } else if (op == 1) {
        Asrc = Kb; Bsrc = Wk; bias = bk; C = Kh;
        m0 = (tile >> 3) * 128; n0 = (tile & 7) * 128;
    } else {
        Asrc = Wv; bias = bv; C = Vt; regB = true;
        m0 = (tile & 7) * 128; n0 = (tile >> 3) * 128;
    }
    Asrc += (size_t)m0 * DMODEL;

    f32x4 acc[4][4];
#pragma unroll
    for (int i = 0; i < 4; i++)
#pragma unroll
        for (int j = 0; j < 4; j++) acc[i][j] = (f32x4)0.0f;

    const int brow = t >> 1, bh2 = t & 1;
    const int ch = (l4 ^ ((l15 >> 1) & 3)) * 8;

    auto writeBrow = [&](int buf, const f32x4* br) {
#pragma unroll
        for (int j = 0; j < 2; j++) {
            f32x4 x = br[2 * j], y = br[2 * j + 1];
            bf16x8 w;
            w[0]=f2bf(x[0]); w[1]=f2bf(x[1]); w[2]=f2bf(x[2]); w[3]=f2bf(x[3]);
            w[4]=f2bf(y[0]); w[5]=f2bf(y[1]); w[6]=f2bf(y[2]); w[7]=f2bf(y[3]);
            const int cp = (bh2 * 2 + j) ^ ((brow >> 1) & 3);
            *(bf16x8*)&Bs[buf][brow * 32 + cp * 8] = w;
        }
    };

    stage32_128(Asrc, 0, (char*)As[0], wid, lane);
    if (!regB) {
        stage32_128(Bsrc + (size_t)n0 * DMODEL, 0, (char*)Bs[0], wid, lane);
    } else {
        f32x4 br[4];
        const f32x4* p = (const f32x4*)&vf[(size_t)(n0 + brow) * DMODEL + bh2 * 16];
#pragma unroll
        for (int j = 0; j < 4; j++) br[j] = p[j];
        writeBrow(0, br);
    }
    __syncthreads();

    int cur = 0;
    for (int kt = 0; kt < DMODEL; kt += 32) {
        const int nxt = cur ^ 1;
        const bool pre = (kt + 32 < DMODEL);
        f32x4 br[4];
        if (pre) {
            stage32_128(Asrc, kt + 32, (char*)As[nxt], wid, lane);
            if (!regB) {
                stage32_128(Bsrc + (size_t)n0 * DMODEL, kt + 32, (char*)Bs[nxt], wid, lane);
            } else {
                const f32x4* p = (const f32x4*)&vf[(size_t)(n0 + brow) * DMODEL + kt + 32 + bh2 * 16];
#pragma unroll
                for (int j = 0; j < 4; j++) br[j] = p[j];
            }
        }

        bf16x8 a[4], b[4];
#pragma unroll
        for (int i = 0; i < 4; i++)
            a[i] = *(const bf16x8*)&As[cur][(wm * 64 + i * 16 + l15) * 32 + ch];
#pragma unroll
        for (int j = 0; j < 4; j++)
            b[j] = *(const bf16x8*)&Bs[cur][(wn * 64 + j * 16 + l15) * 32 + ch];
#pragma unroll
        for (int i = 0; i < 4; i++)
#pragma unroll
            for (int j = 0; j < 4; j++)
                acc[i][j] = __builtin_amdgcn_mfma_f32_16x16x32_bf16(a[i], b[j], acc[i][j], 0, 0, 0);

        if (pre && regB) writeBrow(nxt, br);
        __syncthreads();
        cur = nxt;
    }

#pragma unroll
    for (int i = 0; i < 4; i++) {
        const int mbase = m0 + wm * 64 + i * 16 + l4 * 4;
#pragma unroll
        for (int j = 0; j < 4; j++) {
            const int n = n0 + wn * 64 + j * 16 + l15;
#pragma unroll
            for (int r = 0; r < 4; r++) {
                const int m = mbase + r;
                if (op < 2) {
                    float y = (acc[i][j][r] + bias[n]) * scale;
                    const int b_ = m >> 11, s_ = m & 2047;
                    const int h_ = n >> 6,  d_ = n & 63;
                    C[((((size_t)b_ * H + h_) * SS + s_) << 6) + d_] = f2bf(y);
                } else {
                    C[(size_t)m * ROWS + n] = f2bf(acc[i][j][r] + bias[m]);
                }
            }
        }
    }
}

// O-projection: OW[4096][1024] fp32 = Oc @ Wo^T + bo. 64x128 tiles, BK=32,
// dbuf (24 KB LDS), 512 blocks XCD-chunked, 3 blocks/CU.
__global__ __launch_bounds__(256, 3)
void oproj(const short* __restrict__ Oc, const short* __restrict__ Wo,
           const float* __restrict__ bo, float* __restrict__ out)
{
    __shared__ short As[2][64 * 32];
    __shared__ short Bs[2][128 * 32];

    const int fbid = blockIdx.x;
    const int vbid = (fbid & 7) * 64 + (fbid >> 3);
    const int m0   = (vbid >> 3) * 64;
    const int n0   = (vbid & 7) * 128;
    const int t    = threadIdx.x;
    const int lane = t & 63;
    const int wid  = t >> 6;
    const int wm   = wid >> 1;
    const int wn   = wid & 1;
    const int l15  = lane & 15;
    const int l4   = lane >> 4;
    const int ch   = (l4 ^ ((l15 >> 1) & 3)) * 8;

    f32x4 acc[2][4];
#pragma unroll
    for (int i = 0; i < 2; i++)
#pragma unroll
        for (int j = 0; j < 4; j++) acc[i][j] = (f32x4)0.0f;

    stage32_64 (Oc + (size_t)m0 * DMODEL, 0, (char*)As[0], wid, lane);
    stage32_128(Wo + (size_t)n0 * DMODEL, 0, (char*)Bs[0], wid, lane);
    __syncthreads();

    int cur = 0;
    for (int kt = 0; kt < DMODEL; kt += 32) {
        const int nxt = cur ^ 1;
        if (kt + 32 < DMODEL) {
            stage32_64 (Oc + (size_t)m0 * DMODEL, kt + 32, (char*)As[nxt], wid, lane);
            stage32_128(Wo + (size_t)n0 * DMODEL, kt + 32, (char*)Bs[nxt], wid, lane);
        }
        bf16x8 a[2], b[4];
#pragma unroll
        for (int i = 0; i < 2; i++)
            a[i] = *(const bf16x8*)&As[cur][(wm * 32 + i * 16 + l15) * 32 + ch];
#pragma unroll
        for (int j = 0; j < 4; j++)
            b[j] = *(const bf16x8*)&Bs[cur][(wn * 64 + j * 16 + l15) * 32 + ch];
#pragma unroll
        for (int i = 0; i < 2; i++)
#pragma unroll
            for (int j = 0; j < 4; j++)
                acc[i][j] = __builtin_amdgcn_mfma_f32_16x16x32_bf16(a[i], b[j], acc[i][j], 0, 0, 0);
        __syncthreads();
        cur = nxt;
    }

#pragma unroll
    for (int i = 0; i < 2; i++) {
        const int mbase = m0 + wm * 32 + i * 16 + l4 * 4;
#pragma unroll
        for (int j = 0; j < 4; j++) {
            const int n = n0 + wn * 64 + j * 16 + l15;
#pragma unroll
            for (int r = 0; r < 4; r++)
                out[(size_t)(mbase + r) * DMODEL + n] = acc[i][j][r] + bo[n];
        }
    }
}

// Flash attention, causal, paired q-tiles, double-buffered K/V, 1 barrier/iter.
// SWAPPED QK^T: S^T = mfma(K,Q) -> each lane owns one q-row (q=l15), 16 kv regs.
// Lane-local softmax (2 shuffles), defer-max THR=8, b64 P writes.
__global__ __launch_bounds__(256, 2)
void attn_fwd(const short* __restrict__ Qh, const short* __restrict__ Kh,
              const short* __restrict__ Vt, short* __restrict__ Oc)
{
    __shared__ short Ks[2][64][64];
    __shared__ short Vs[2][64][64];
    __shared__ short Ps[4][16][72];   // [wave][q_local][kv]

    const int t    = threadIdx.x;
    const int lane = t & 63;
    const int wid  = t >> 6;
    const int fbid = blockIdx.x;
    const int vbid = (fbid & 7) * 64 + (fbid >> 3);
    const int bh   = vbid >> 4;
    const int qp   = vbid & 15;
    const int b    = bh >> 4;
    const int h    = bh & 15;
    const int l15  = lane & 15;
    const int l4   = lane >> 4;

    const int srow = wid * 8 + (lane >> 3);
    const int sch  = lane & 7;
    const int ldsoff = wid * 1024;

    auto stage = [&](int buf, int kvt) {
#pragma unroll
        for (int i = 0; i < 2; i++) {
            const int row = i * 32 + srow;
            const int chg = sch ^ (row & 7);
            gload_lds16(&Kh[((size_t)bh * SS + kvt * 64 + row) * 64 + chg * 8],
                        (char*)Ks + buf * 8192 + ldsoff + i * 4096);
            gload_lds16(&Vt[((size_t)(h * 64 + row)) * ROWS + b * SS + kvt * 64 + chg * 8],
                        (char*)Vs + buf * 8192 + ldsoff + i * 4096);
        }
    };

    for (int half = 0; half < 2; ++half) {
        const int qt = half ? (31 - qp) : qp;

        bf16x8 qa[2];
        {
            const int qrow = qt * 64 + wid * 16 + l15;
            const size_t base = ((size_t)bh * SS + qrow) * 64;
            qa[0] = *(const bf16x8*)&Qh[base + l4 * 8];
            qa[1] = *(const bf16x8*)&Qh[base + 32 + l4 * 8];
        }

        f32x4 accO[4];
#pragma unroll
        for (int i = 0; i < 4; i++) accO[i] = (f32x4)0.f;
        float mrun = -1e30f, lrun = 0.f;   // state for q-row = wid*16 + l15

        stage(0, 0);
        __syncthreads();

        int cur = 0;
        for (int kvt = 0; kvt <= qt; ++kvt) {
            if (kvt < qt) stage(cur ^ 1, kvt + 1);

            // S^T tile: sc[fn][r] = S[kv = fn*16 + l4*4 + r][q = wid*16 + l15]
            f32x4 sc[4];
#pragma unroll
            for (int i = 0; i < 4; i++) sc[i] = (f32x4)0.f;
            __builtin_amdgcn_s_setprio(1);
#pragma unroll
            for (int kk = 0; kk < 2; kk++) {
#pragma unroll
                for (int fn = 0; fn < 4; fn++) {
                    const int chk = (kk * 4 + l4) ^ (l15 & 7);
                    bf16x8 kb = *(const bf16x8*)&Ks[cur][fn * 16 + l15][chk * 8];
                    sc[fn] = __builtin_amdgcn_mfma_f32_16x16x32_bf16(kb, qa[kk], sc[fn], 0, 0, 0);
                }
            }
            __builtin_amdgcn_s_setprio(0);

            if (kvt == qt) {   // causal: kv_local > q_local -> masked
                const int qg = wid * 16 + l15;
#pragma unroll
                for (int fn = 0; fn < 4; fn++)
#pragma unroll
                    for (int r = 0; r < 4; r++)
                        if (fn * 16 + l4 * 4 + r > qg) sc[fn][r] = -1e30f;
            }

            // lane-local row max + 2-shuffle reduce across l4 groups
            float pmax = sc[0][0];
#pragma unroll
            for (int fn = 0; fn < 4; fn++)
#pragma unroll
                for (int r = 0; r < 4; r++)
                    pmax = fmaxf(pmax, sc[fn][r]);
            pmax = fmaxf(pmax, __shfl_xor(pmax, 16));
            pmax = fmaxf(pmax, __shfl_xor(pmax, 32));

            // defer-max: rescale only when max grew by > 8
            if (__any(pmax > mrun + 8.0f)) {
                const float mn = fmaxf(mrun, pmax);
                const float es = __expf(mrun - mn);
                mrun = mn;
                lrun *= es;
                float esr[4];
#pragma unroll
                for (int r = 0; r < 4; r++) esr[r] = __shfl(es, l4 * 4 + r);
#pragma unroll
                for (int fd = 0; fd < 4; fd++)
#pragma unroll
                    for (int r = 0; r < 4; r++) accO[fd][r] *= esr[r];
            }

            float rs = 0.f;
#pragma unroll
            for (int fn = 0; fn < 4; fn++)
#pragma unroll
                for (int r = 0; r < 4; r++) {
                    const float p = __expf(sc[fn][r] - mrun);
                    sc[fn][r] = p;
                    rs += p;
                }
            rs += __shfl_xor(rs, 16);
            rs += __shfl_xor(rs, 32);
            lrun += rs;

            // P -> per-wave LDS, 4 consecutive kv per lane = b64 writes
#pragma unroll
            for (int fn = 0; fn < 4; fn++) {
                short4v w4;
                w4[0] = f2bf(sc[fn][0]); w4[1] = f2bf(sc[fn][1]);
                w4[2] = f2bf(sc[fn][2]); w4[3] = f2bf(sc[fn][3]);
                *(short4v*)&Ps[wid][l15][fn * 16 + l4 * 4] = w4;
            }

            __builtin_amdgcn_s_setprio(1);
#pragma unroll
            for (int kk = 0; kk < 2; kk++) {
                bf16x8 pa = *(const bf16x8*)&Ps[wid][l15][kk * 32 + l4 * 8];
#pragma unroll
                for (int fd = 0; fd < 4; fd++) {
                    const int chk = (kk * 4 + l4) ^ (l15 & 7);
                    bf16x8 vb = *(const bf16x8*)&Vs[cur][fd * 16 + l15][chk * 8];
                    accO[fd] = __builtin_amdgcn_mfma_f32_16x16x32_bf16(pa, vb, accO[fd], 0, 0, 0);
                }
            }
            __builtin_amdgcn_s_setprio(0);

            __syncthreads();
            cur ^= 1;
        }

        // epilogue: accO rows are q_local = l4*4 + r; lrun lives at lane l15=q_local
        float linv[4];
#pragma unroll
        for (int r = 0; r < 4; r++) linv[r] = 1.0f / __shfl(lrun, l4 * 4 + r);
#pragma unroll
        for (int fd = 0; fd < 4; fd++)
#pragma unroll
            for (int r = 0; r < 4; r++) {
                const int q = qt * 64 + wid * 16 + l4 * 4 + r;
                const size_t idx = ((size_t)b * SS + q) * DMODEL + h * 64 + fd * 16 + l15;
                Oc[idx] = f2bf(accO[fd][r] * linv[r]);
            }
    }
}

extern "C" void kernel_launch(void* const* d_in, const int* in_sizes, int n_in,
                              void* d_out, int out_size, void* d_ws, size_t ws_size,
                              hipStream_t stream) {
    const float* q   = (const float*)d_in[0];
    const float* k   = (const float*)d_in[1];
    const float* v   = (const float*)d_in[2];
    const float* w_q = (const float*)d_in[4];
    const float* b_q = (const float*)d_in[5];
    const float* w_k = (const float*)d_in[6];
    const float* b_k = (const float*)d_in[7];
    const float* w_v = (const float*)d_in[8];
    const float* b_v = (const float*)d_in[9];
    const float* w_o = (const float*)d_in[10];
    const float* b_o = (const float*)d_in[11];

    const size_t T = (size_t)ROWS * DMODEL;   // 4M elements
    const size_t W = (size_t)DMODEL * DMODEL; // 1M elements
    short* Qh  = (short*)d_ws;
    short* Kh  = Qh + T;
    short* Vt  = Kh + T;
    short* Wb  = Vt + T;
    short* Wq16 = Wb, *Wk16 = Wb + W, *Wv16 = Wb + 2 * W, *Wo16 = Wb + 3 * W;
    short* Qb  = (short*)d_out;
    short* Kb  = Qb + T;
    short* Oc  = (short*)d_out;
    float* OW  = (float*)d_ws;                // oproj fp32 result (over dead Qh/Kh)

    dim3 blk(256);
    cvt<<<dim3(6144), blk, 0, stream>>>(q, k, w_q, w_k, w_v, w_o, Qb, Kb, Wb);
    qkv_proj<<<dim3(768), blk, 0, stream>>>(Qb, Kb, v, Wq16, Wk16, Wv16,
                                            b_q, b_k, b_v, Qh, Kh, Vt);
    attn_fwd<<<dim3(512), blk, 0, stream>>>(Qh, Kh, Vt, Oc);
    oproj<<<dim3(512), blk, 0, stream>>>(Oc, Wo16, b_o, OW);
    hipMemcpyAsync(d_out, d_ws, (size_t)ROWS * DMODEL * sizeof(float),
                   hipMemcpyDeviceToDevice, stream);
}

// Round 9
// 258.980 us; speedup vs baseline: 1.2034x; 1.0128x over previous
//
#include <hip/hip_runtime.h>
#include <hip/hip_bf16.h>

#define H 16
#define BB 2
#define SS 2048
#define DMODEL 1024
#define ROWS (BB * SS)   // 4096

typedef __attribute__((ext_vector_type(8))) short bf16x8;
typedef __attribute__((ext_vector_type(4))) short short4v;
typedef __attribute__((ext_vector_type(4))) float f32x4;

__device__ __forceinline__ short f2bf(float f) {
    union { float f; unsigned u; } v; v.f = f;
    unsigned r = v.u + 0x7fffu + ((v.u >> 16) & 1u);
    return (short)(r >> 16);
}

__device__ __forceinline__ void gload_lds16(const void* g, void* l) {
    __builtin_amdgcn_global_load_lds(
        (const __attribute__((address_space(1))) char*)g,
        (__attribute__((address_space(3))) char*)l, 16, 0, 0);
}

// fp32 -> bf16: q,k (4M each) and 4 weight matrices (1M each).
__global__ __launch_bounds__(256)
void cvt(const float* __restrict__ q, const float* __restrict__ k,
         const float* __restrict__ wq, const float* __restrict__ wk,
         const float* __restrict__ wv, const float* __restrict__ wo,
         short* __restrict__ Qb, short* __restrict__ Kb, short* __restrict__ Wb)
{
    const int bid = blockIdx.x;
    const float* s; short* d; int lb;
    if (bid < 2048)      { s = q; d = Qb; lb = bid; }
    else if (bid < 4096) { s = k; d = Kb; lb = bid - 2048; }
    else {
        const int w = (bid - 4096) >> 9;
        lb = (bid - 4096) & 511;
        s = (w == 0) ? wq : (w == 1) ? wk : (w == 2) ? wv : wo;
        d = Wb + (size_t)w * (DMODEL * DMODEL);
    }
    const int p = lb * 256 + threadIdx.x;
    const f32x4* sv = (const f32x4*)s;
    f32x4 a = sv[2 * p], c = sv[2 * p + 1];
    bf16x8 o;
    o[0] = f2bf(a[0]); o[1] = f2bf(a[1]); o[2] = f2bf(a[2]); o[3] = f2bf(a[3]);
    o[4] = f2bf(c[0]); o[5] = f2bf(c[1]); o[6] = f2bf(c[2]); o[7] = f2bf(c[3]);
    ((bf16x8*)d)[p] = o;
}

// BK=32 stagers. LDS tile [R][32] shorts; physical chunk of row r, logical c:
// c ^ ((r>>1)&3)  -> conflict-free b128 frag reads. Swizzle on global source.
__device__ __forceinline__ void stage32_128(const short* __restrict__ src, int kt,
                                            char* lds, int wid, int lane)
{
#pragma unroll
    for (int i = 0; i < 2; i++) {
        const int blk = wid * 2 + i;
        const int row = blk * 16 + (lane >> 2);
        const int g   = (lane & 3) ^ ((lane >> 3) & 3);
        gload_lds16(&src[(size_t)row * DMODEL + kt + g * 8], lds + blk * 1024);
    }
}

__device__ __forceinline__ void stage32_64(const short* __restrict__ src, int kt,
                                           char* lds, int wid, int lane)
{
    const int row = wid * 16 + (lane >> 2);
    const int g   = (lane & 3) ^ ((lane >> 3) & 3);
    gload_lds16(&src[(size_t)row * DMODEL + kt + g * 8], lds + wid * 1024);
}

// Fused Q/K/V projection. 768 blocks, op = fbid%3 (round-robin -> XCD-balanced).
// op 0/1: counted-vmcnt 2-ahead triple-buffer pipeline (T3+T4).
// op 2:   drain-style dbuf (B = v fp32 reg-staged).
__global__ __launch_bounds__(256, 3)
void qkv_proj(const short* __restrict__ Qb, const short* __restrict__ Kb,
              const float* __restrict__ vf,
              const short* __restrict__ Wq, const short* __restrict__ Wk,
              const short* __restrict__ Wv,
              const float* __restrict__ bq, const float* __restrict__ bk,
              const float* __restrict__ bv,
              short* __restrict__ Qh, short* __restrict__ Kh,
              short* __restrict__ Vt)
{
    __shared__ short As[3][128 * 32];
    __shared__ short Bs[3][128 * 32];

    const int fbid = blockIdx.x;
    const int op   = fbid % 3;
    const int tile = fbid / 3;          // 0..255
    const int t    = threadIdx.x;
    const int lane = t & 63;
    const int wid  = t >> 6;
    const int wm   = wid >> 1;
    const int wn   = wid & 1;
    const int l15  = lane & 15;
    const int l4   = lane >> 4;

    const short* Asrc; const short* Bsrc = nullptr; const float* bias;
    short* C; int m0, n0; float scale = 1.0f;
    if (op == 0) {
        Asrc = Qb; Bsrc = Wq; bias = bq; C = Qh;
        m0 = (tile >> 3) * 128; n0 = (tile & 7) * 128; scale = 0.125f;
    } else if (op == 1) {
        Asrc = Kb; Bsrc = Wk; bias = bk; C = Kh;
        m0 = (tile >> 3) * 128; n0 = (tile & 7) * 128;
    } else {
        Asrc = Wv; bias = bv; C = Vt;
        m0 = (tile & 7) * 128; n0 = (tile >> 3) * 128;
    }
    Asrc += (size_t)m0 * DMODEL;

    f32x4 acc[4][4];
#pragma unroll
    for (int i = 0; i < 4; i++)
#pragma unroll
        for (int j = 0; j < 4; j++) acc[i][j] = (f32x4)0.0f;

    const int ch = (l4 ^ ((l15 >> 1) & 3)) * 8;

    if (op < 2) {
        // ---- counted-vmcnt 2-ahead pipeline; 4 vmem issues/wave per stage ----
        const short* Bp = Bsrc + (size_t)n0 * DMODEL;
        stage32_128(Asrc, 0,  (char*)As[0], wid, lane);
        stage32_128(Bp,   0,  (char*)Bs[0], wid, lane);
        stage32_128(Asrc, 32, (char*)As[1], wid, lane);
        stage32_128(Bp,   32, (char*)Bs[1], wid, lane);
        for (int it = 0; it < 32; ++it) {
            if (it < 31) asm volatile("s_waitcnt vmcnt(4)" ::: "memory");
            else         asm volatile("s_waitcnt vmcnt(0)" ::: "memory");
            __builtin_amdgcn_s_barrier();
            __builtin_amdgcn_sched_barrier(0);
            if (it + 2 < 32) {
                const int nb = (it + 2) % 3;
                stage32_128(Asrc, (it + 2) * 32, (char*)As[nb], wid, lane);
                stage32_128(Bp,   (it + 2) * 32, (char*)Bs[nb], wid, lane);
            }
            const short* Ab = As[it % 3];
            const short* Bb = Bs[it % 3];
            bf16x8 a[4], b[4];
#pragma unroll
            for (int i = 0; i < 4; i++)
                a[i] = *(const bf16x8*)&Ab[(wm * 64 + i * 16 + l15) * 32 + ch];
#pragma unroll
            for (int j = 0; j < 4; j++)
                b[j] = *(const bf16x8*)&Bb[(wn * 64 + j * 16 + l15) * 32 + ch];
            __builtin_amdgcn_s_setprio(1);
#pragma unroll
            for (int i = 0; i < 4; i++)
#pragma unroll
                for (int j = 0; j < 4; j++)
                    acc[i][j] = __builtin_amdgcn_mfma_f32_16x16x32_bf16(a[i], b[j], acc[i][j], 0, 0, 0);
            __builtin_amdgcn_s_setprio(0);
        }
    } else {
        // ---- drain-style dbuf (buffers 0/1), B = v fp32 reg-staged ----
        const int brow = t >> 1, bh2 = t & 1;
        auto writeBrow = [&](int buf, const f32x4* br) {
#pragma unroll
            for (int j = 0; j < 2; j++) {
                f32x4 x = br[2 * j], y = br[2 * j + 1];
                bf16x8 w;
                w[0]=f2bf(x[0]); w[1]=f2bf(x[1]); w[2]=f2bf(x[2]); w[3]=f2bf(x[3]);
                w[4]=f2bf(y[0]); w[5]=f2bf(y[1]); w[6]=f2bf(y[2]); w[7]=f2bf(y[3]);
                const int cp = (bh2 * 2 + j) ^ ((brow >> 1) & 3);
                *(bf16x8*)&Bs[buf][brow * 32 + cp * 8] = w;
            }
        };

        stage32_128(Asrc, 0, (char*)As[0], wid, lane);
        {
            f32x4 br[4];
            const f32x4* p = (const f32x4*)&vf[(size_t)(n0 + brow) * DMODEL + bh2 * 16];
#pragma unroll
            for (int j = 0; j < 4; j++) br[j] = p[j];
            writeBrow(0, br);
        }
        __syncthreads();

        int cur = 0;
        for (int kt = 0; kt < DMODEL; kt += 32) {
            const int nxt = cur ^ 1;
            const bool pre = (kt + 32 < DMODEL);
            f32x4 br[4];
            if (pre) {
                stage32_128(Asrc, kt + 32, (char*)As[nxt], wid, lane);
                const f32x4* p = (const f32x4*)&vf[(size_t)(n0 + brow) * DMODEL + kt + 32 + bh2 * 16];
#pragma unroll
                for (int j = 0; j < 4; j++) br[j] = p[j];
            }

            bf16x8 a[4], b[4];
#pragma unroll
            for (int i = 0; i < 4; i++)
                a[i] = *(const bf16x8*)&As[cur][(wm * 64 + i * 16 + l15) * 32 + ch];
#pragma unroll
            for (int j = 0; j < 4; j++)
                b[j] = *(const bf16x8*)&Bs[cur][(wn * 64 + j * 16 + l15) * 32 + ch];
#pragma unroll
            for (int i = 0; i < 4; i++)
#pragma unroll
                for (int j = 0; j < 4; j++)
                    acc[i][j] = __builtin_amdgcn_mfma_f32_16x16x32_bf16(a[i], b[j], acc[i][j], 0, 0, 0);

            if (pre) writeBrow(nxt, br);
            __syncthreads();
            cur = nxt;
        }
    }

#pragma unroll
    for (int i = 0; i < 4; i++) {
        const int mbase = m0 + wm * 64 + i * 16 + l4 * 4;
#pragma unroll
        for (int j = 0; j < 4; j++) {
            const int n = n0 + wn * 64 + j * 16 + l15;
#pragma unroll
            for (int r = 0; r < 4; r++) {
                const int m = mbase + r;
                if (op < 2) {
                    float y = (acc[i][j][r] + bias[n]) * scale;
                    const int b_ = m >> 11, s_ = m & 2047;
                    const int h_ = n >> 6,  d_ = n & 63;
                    C[((((size_t)b_ * H + h_) * SS + s_) << 6) + d_] = f2bf(y);
                } else {
                    C[(size_t)m * ROWS + n] = f2bf(acc[i][j][r] + bias[m]);
                }
            }
        }
    }
}

// O-projection: OW[4096][1024] fp32 = Oc @ Wo^T + bo. 64x128 tiles, BK=32,
// counted-vmcnt 2-ahead triple-buffer, 512 blocks XCD-chunked.
__global__ __launch_bounds__(256, 3)
void oproj(const short* __restrict__ Oc, const short* __restrict__ Wo,
           const float* __restrict__ bo, float* __restrict__ out)
{
    __shared__ short As[3][64 * 32];
    __shared__ short Bs[3][128 * 32];

    const int fbid = blockIdx.x;
    const int vbid = (fbid & 7) * 64 + (fbid >> 3);
    const int m0   = (vbid >> 3) * 64;
    const int n0   = (vbid & 7) * 128;
    const int t    = threadIdx.x;
    const int lane = t & 63;
    const int wid  = t >> 6;
    const int wm   = wid >> 1;
    const int wn   = wid & 1;
    const int l15  = lane & 15;
    const int l4   = lane >> 4;
    const int ch   = (l4 ^ ((l15 >> 1) & 3)) * 8;

    f32x4 acc[2][4];
#pragma unroll
    for (int i = 0; i < 2; i++)
#pragma unroll
        for (int j = 0; j < 4; j++) acc[i][j] = (f32x4)0.0f;

    const short* Ap = Oc + (size_t)m0 * DMODEL;
    const short* Bp = Wo + (size_t)n0 * DMODEL;

    stage32_64 (Ap, 0,  (char*)As[0], wid, lane);
    stage32_128(Bp, 0,  (char*)Bs[0], wid, lane);
    stage32_64 (Ap, 32, (char*)As[1], wid, lane);
    stage32_128(Bp, 32, (char*)Bs[1], wid, lane);

    for (int it = 0; it < 32; ++it) {
        if (it < 31) asm volatile("s_waitcnt vmcnt(3)" ::: "memory");
        else         asm volatile("s_waitcnt vmcnt(0)" ::: "memory");
        __builtin_amdgcn_s_barrier();
        __builtin_amdgcn_sched_barrier(0);
        if (it + 2 < 32) {
            const int nb = (it + 2) % 3;
            stage32_64 (Ap, (it + 2) * 32, (char*)As[nb], wid, lane);
            stage32_128(Bp, (it + 2) * 32, (char*)Bs[nb], wid, lane);
        }
        const short* Ab = As[it % 3];
        const short* Bb = Bs[it % 3];
        bf16x8 a[2], b[4];
#pragma unroll
        for (int i = 0; i < 2; i++)
            a[i] = *(const bf16x8*)&Ab[(wm * 32 + i * 16 + l15) * 32 + ch];
#pragma unroll
        for (int j = 0; j < 4; j++)
            b[j] = *(const bf16x8*)&Bb[(wn * 64 + j * 16 + l15) * 32 + ch];
        __builtin_amdgcn_s_setprio(1);
#pragma unroll
        for (int i = 0; i < 2; i++)
#pragma unroll
            for (int j = 0; j < 4; j++)
                acc[i][j] = __builtin_amdgcn_mfma_f32_16x16x32_bf16(a[i], b[j], acc[i][j], 0, 0, 0);
        __builtin_amdgcn_s_setprio(0);
    }

#pragma unroll
    for (int i = 0; i < 2; i++) {
        const int mbase = m0 + wm * 32 + i * 16 + l4 * 4;
#pragma unroll
        for (int j = 0; j < 4; j++) {
            const int n = n0 + wn * 64 + j * 16 + l15;
#pragma unroll
            for (int r = 0; r < 4; r++)
                out[(size_t)(mbase + r) * DMODEL + n] = acc[i][j][r] + bo[n];
        }
    }
}

// Flash attention, causal, paired q-tiles, double-buffered K/V, 1 barrier/iter.
// SWAPPED QK^T: S^T = mfma(K,Q) -> each lane owns one q-row (q=l15), 16 kv regs.
__global__ __launch_bounds__(256, 2)
void attn_fwd(const short* __restrict__ Qh, const short* __restrict__ Kh,
              const short* __restrict__ Vt, short* __restrict__ Oc)
{
    __shared__ short Ks[2][64][64];
    __shared__ short Vs[2][64][64];
    __shared__ short Ps[4][16][72];   // [wave][q_local][kv]

    const int t    = threadIdx.x;
    const int lane = t & 63;
    const int wid  = t >> 6;
    const int fbid = blockIdx.x;
    const int vbid = (fbid & 7) * 64 + (fbid >> 3);
    const int bh   = vbid >> 4;
    const int qp   = vbid & 15;
    const int b    = bh >> 4;
    const int h    = bh & 15;
    const int l15  = lane & 15;
    const int l4   = lane >> 4;

    const int srow = wid * 8 + (lane >> 3);
    const int sch  = lane & 7;
    const int ldsoff = wid * 1024;

    auto stage = [&](int buf, int kvt) {
#pragma unroll
        for (int i = 0; i < 2; i++) {
            const int row = i * 32 + srow;
            const int chg = sch ^ (row & 7);
            gload_lds16(&Kh[((size_t)bh * SS + kvt * 64 + row) * 64 + chg * 8],
                        (char*)Ks + buf * 8192 + ldsoff + i * 4096);
            gload_lds16(&Vt[((size_t)(h * 64 + row)) * ROWS + b * SS + kvt * 64 + chg * 8],
                        (char*)Vs + buf * 8192 + ldsoff + i * 4096);
        }
    };

    for (int half = 0; half < 2; ++half) {
        const int qt = half ? (31 - qp) : qp;

        bf16x8 qa[2];
        {
            const int qrow = qt * 64 + wid * 16 + l15;
            const size_t base = ((size_t)bh * SS + qrow) * 64;
            qa[0] = *(const bf16x8*)&Qh[base + l4 * 8];
            qa[1] = *(const bf16x8*)&Qh[base + 32 + l4 * 8];
        }

        f32x4 accO[4];
#pragma unroll
        for (int i = 0; i < 4; i++) accO[i] = (f32x4)0.f;
        float mrun = -1e30f, lrun = 0.f;

        stage(0, 0);
        __syncthreads();

        int cur = 0;
        for (int kvt = 0; kvt <= qt; ++kvt) {
            if (kvt < qt) stage(cur ^ 1, kvt + 1);

            f32x4 sc[4];
#pragma unroll
            for (int i = 0; i < 4; i++) sc[i] = (f32x4)0.f;
            __builtin_amdgcn_s_setprio(1);
#pragma unroll
            for (int kk = 0; kk < 2; kk++) {
#pragma unroll
                for (int fn = 0; fn < 4; fn++) {
                    const int chk = (kk * 4 + l4) ^ (l15 & 7);
                    bf16x8 kb = *(const bf16x8*)&Ks[cur][fn * 16 + l15][chk * 8];
                    sc[fn] = __builtin_amdgcn_mfma_f32_16x16x32_bf16(kb, qa[kk], sc[fn], 0, 0, 0);
                }
            }
            __builtin_amdgcn_s_setprio(0);

            if (kvt == qt) {
                const int qg = wid * 16 + l15;
#pragma unroll
                for (int fn = 0; fn < 4; fn++)
#pragma unroll
                    for (int r = 0; r < 4; r++)
                        if (fn * 16 + l4 * 4 + r > qg) sc[fn][r] = -1e30f;
            }

            float pmax = sc[0][0];
#pragma unroll
            for (int fn = 0; fn < 4; fn++)
#pragma unroll
                for (int r = 0; r < 4; r++)
                    pmax = fmaxf(pmax, sc[fn][r]);
            pmax = fmaxf(pmax, __shfl_xor(pmax, 16));
            pmax = fmaxf(pmax, __shfl_xor(pmax, 32));

            if (__any(pmax > mrun + 8.0f)) {
                const float mn = fmaxf(mrun, pmax);
                const float es = __expf(mrun - mn);
                mrun = mn;
                lrun *= es;
                float esr[4];
#pragma unroll
                for (int r = 0; r < 4; r++) esr[r] = __shfl(es, l4 * 4 + r);
#pragma unroll
                for (int fd = 0; fd < 4; fd++)
#pragma unroll
                    for (int r = 0; r < 4; r++) accO[fd][r] *= esr[r];
            }

            float rs = 0.f;
#pragma unroll
            for (int fn = 0; fn < 4; fn++)
#pragma unroll
                for (int r = 0; r < 4; r++) {
                    const float p = __expf(sc[fn][r] - mrun);
                    sc[fn][r] = p;
                    rs += p;
                }
            rs += __shfl_xor(rs, 16);
            rs += __shfl_xor(rs, 32);
            lrun += rs;

#pragma unroll
            for (int fn = 0; fn < 4; fn++) {
                short4v w4;
                w4[0] = f2bf(sc[fn][0]); w4[1] = f2bf(sc[fn][1]);
                w4[2] = f2bf(sc[fn][2]); w4[3] = f2bf(sc[fn][3]);
                *(short4v*)&Ps[wid][l15][fn * 16 + l4 * 4] = w4;
            }

            __builtin_amdgcn_s_setprio(1);
#pragma unroll
            for (int kk = 0; kk < 2; kk++) {
                bf16x8 pa = *(const bf16x8*)&Ps[wid][l15][kk * 32 + l4 * 8];
#pragma unroll
                for (int fd = 0; fd < 4; fd++) {
                    const int chk = (kk * 4 + l4) ^ (l15 & 7);
                    bf16x8 vb = *(const bf16x8*)&Vs[cur][fd * 16 + l15][chk * 8];
                    accO[fd] = __builtin_amdgcn_mfma_f32_16x16x32_bf16(pa, vb, accO[fd], 0, 0, 0);
                }
            }
            __builtin_amdgcn_s_setprio(0);

            __syncthreads();
            cur ^= 1;
        }

        float linv[4];
#pragma unroll
        for (int r = 0; r < 4; r++) linv[r] = 1.0f / __shfl(lrun, l4 * 4 + r);
#pragma unroll
        for (int fd = 0; fd < 4; fd++)
#pragma unroll
            for (int r = 0; r < 4; r++) {
                const int q = qt * 64 + wid * 16 + l4 * 4 + r;
                const size_t idx = ((size_t)b * SS + q) * DMODEL + h * 64 + fd * 16 + l15;
                Oc[idx] = f2bf(accO[fd][r] * linv[r]);
            }
    }
}

extern "C" void kernel_launch(void* const* d_in, const int* in_sizes, int n_in,
                              void* d_out, int out_size, void* d_ws, size_t ws_size,
                              hipStream_t stream) {
    const float* q   = (const float*)d_in[0];
    const float* k   = (const float*)d_in[1];
    const float* v   = (const float*)d_in[2];
    const float* w_q = (const float*)d_in[4];
    const float* b_q = (const float*)d_in[5];
    const float* w_k = (const float*)d_in[6];
    const float* b_k = (const float*)d_in[7];
    const float* w_v = (const float*)d_in[8];
    const float* b_v = (const float*)d_in[9];
    const float* w_o = (const float*)d_in[10];
    const float* b_o = (const float*)d_in[11];

    const size_t T = (size_t)ROWS * DMODEL;   // 4M elements
    const size_t W = (size_t)DMODEL * DMODEL; // 1M elements
    short* Qh  = (short*)d_ws;
    short* Kh  = Qh + T;
    short* Vt  = Kh + T;
    short* Wb  = Vt + T;
    short* Wq16 = Wb, *Wk16 = Wb + W, *Wv16 = Wb + 2 * W, *Wo16 = Wb + 3 * W;
    short* Qb  = (short*)d_out;
    short* Kb  = Qb + T;
    short* Oc  = (short*)d_out;
    float* OW  = (float*)d_ws;                // oproj fp32 result (over dead Qh/Kh)

    dim3 blk(256);
    cvt<<<dim3(6144), blk, 0, stream>>>(q, k, w_q, w_k, w_v, w_o, Qb, Kb, Wb);
    qkv_proj<<<dim3(768), blk, 0, stream>>>(Qb, Kb, v, Wq16, Wk16, Wv16,
                                            b_q, b_k, b_v, Qh, Kh, Vt);
    attn_fwd<<<dim3(512), blk, 0, stream>>>(Qh, Kh, Vt, Oc);
    oproj<<<dim3(512), blk, 0, stream>>>(Oc, Wo16, b_o, OW);
    hipMemcpyAsync(d_out, d_ws, (size_t)ROWS * DMODEL * sizeof(float),
                   hipMemcpyDeviceToDevice, stream);
}

// Round 10
// 251.143 us; speedup vs baseline: 1.2409x; 1.0312x over previous
//
#include <hip/hip_runtime.h>
#include <hip/hip_bf16.h>

#define H 16
#define BB 2
#define SS 2048
#define DMODEL 1024
#define ROWS (BB * SS)   // 4096

typedef __attribute__((ext_vector_type(8))) short bf16x8;
typedef __attribute__((ext_vector_type(4))) short short4v;
typedef __attribute__((ext_vector_type(4))) float f32x4;

__device__ __forceinline__ short f2bf(float f) {
    union { float f; unsigned u; } v; v.f = f;
    unsigned r = v.u + 0x7fffu + ((v.u >> 16) & 1u);
    return (short)(r >> 16);
}

__device__ __forceinline__ void gload_lds16(const void* g, void* l) {
    __builtin_amdgcn_global_load_lds(
        (const __attribute__((address_space(1))) char*)g,
        (__attribute__((address_space(3))) char*)l, 16, 0, 0);
}

// fp32 -> bf16: q,k (4M each) and 4 weight matrices (1M each).
__global__ __launch_bounds__(256)
void cvt(const float* __restrict__ q, const float* __restrict__ k,
         const float* __restrict__ wq, const float* __restrict__ wk,
         const float* __restrict__ wv, const float* __restrict__ wo,
         short* __restrict__ Qb, short* __restrict__ Kb, short* __restrict__ Wb)
{
    const int bid = blockIdx.x;
    const float* s; short* d; int lb;
    if (bid < 2048)      { s = q; d = Qb; lb = bid; }
    else if (bid < 4096) { s = k; d = Kb; lb = bid - 2048; }
    else {
        const int w = (bid - 4096) >> 9;
        lb = (bid - 4096) & 511;
        s = (w == 0) ? wq : (w == 1) ? wk : (w == 2) ? wv : wo;
        d = Wb + (size_t)w * (DMODEL * DMODEL);
    }
    const int p = lb * 256 + threadIdx.x;
    const f32x4* sv = (const f32x4*)s;
    f32x4 a = sv[2 * p], c = sv[2 * p + 1];
    bf16x8 o;
    o[0] = f2bf(a[0]); o[1] = f2bf(a[1]); o[2] = f2bf(a[2]); o[3] = f2bf(a[3]);
    o[4] = f2bf(c[0]); o[5] = f2bf(c[1]); o[6] = f2bf(c[2]); o[7] = f2bf(c[3]);
    ((bf16x8*)d)[p] = o;
}

// BK=32 stagers. LDS tile [R][32] shorts; physical chunk of row r, logical c:
// c ^ ((r>>1)&3)  -> conflict-free b128 frag reads. Swizzle on global source.
__device__ __forceinline__ void stage32_128(const short* __restrict__ src, int kt,
                                            char* lds, int wid, int lane)
{
#pragma unroll
    for (int i = 0; i < 2; i++) {
        const int blk = wid * 2 + i;
        const int row = blk * 16 + (lane >> 2);
        const int g   = (lane & 3) ^ ((lane >> 3) & 3);
        gload_lds16(&src[(size_t)row * DMODEL + kt + g * 8], lds + blk * 1024);
    }
}

__device__ __forceinline__ void stage32_64(const short* __restrict__ src, int kt,
                                           char* lds, int wid, int lane)
{
    const int row = wid * 16 + (lane >> 2);
    const int g   = (lane & 3) ^ ((lane >> 3) & 3);
    gload_lds16(&src[(size_t)row * DMODEL + kt + g * 8], lds + wid * 1024);
}

// Fused Q/K/V projection. 768 blocks. XCD-balanced AND panel-local mapping:
// xcd = fbid&7 gets 32 tiles of EACH op; within an XCD each op's tiles span
// one 512-row activation panel (1-2 MB) + its 2 MB weight -> L2-resident.
// op 0/1: counted-vmcnt 2-ahead triple-buffer pipeline (T3+T4).
// op 2:   drain-style dbuf (B = v fp32 reg-staged).
__global__ __launch_bounds__(256, 3)
void qkv_proj(const short* __restrict__ Qb, const short* __restrict__ Kb,
              const float* __restrict__ vf,
              const short* __restrict__ Wq, const short* __restrict__ Wk,
              const short* __restrict__ Wv,
              const float* __restrict__ bq, const float* __restrict__ bk,
              const float* __restrict__ bv,
              short* __restrict__ Qh, short* __restrict__ Kh,
              short* __restrict__ Vt)
{
    __shared__ short As[3][128 * 32];
    __shared__ short Bs[3][128 * 32];

    const int fbid = blockIdx.x;
    const int xcd  = fbid & 7;
    const int slot = fbid >> 3;         // 0..95
    const int op   = slot % 3;
    const int idx  = slot / 3;          // 0..31
    const int t    = threadIdx.x;
    const int lane = t & 63;
    const int wid  = t >> 6;
    const int wm   = wid >> 1;
    const int wn   = wid & 1;
    const int l15  = lane & 15;
    const int l4   = lane >> 4;

    const short* Asrc; const short* Bsrc = nullptr; const float* bias;
    short* C; int m0, n0; float scale = 1.0f;
    if (op == 0) {
        Asrc = Qb; Bsrc = Wq; bias = bq; C = Qh;
        m0 = (xcd * 4 + (idx >> 3)) * 128; n0 = (idx & 7) * 128; scale = 0.125f;
    } else if (op == 1) {
        Asrc = Kb; Bsrc = Wk; bias = bk; C = Kh;
        m0 = (xcd * 4 + (idx >> 3)) * 128; n0 = (idx & 7) * 128;
    } else {
        Asrc = Wv; bias = bv; C = Vt;
        m0 = (idx & 7) * 128; n0 = (xcd * 4 + (idx >> 3)) * 128;
    }
    Asrc += (size_t)m0 * DMODEL;

    f32x4 acc[4][4];
#pragma unroll
    for (int i = 0; i < 4; i++)
#pragma unroll
        for (int j = 0; j < 4; j++) acc[i][j] = (f32x4)0.0f;

    const int ch = (l4 ^ ((l15 >> 1) & 3)) * 8;

    if (op < 2) {
        // ---- counted-vmcnt 2-ahead pipeline; 4 vmem issues/wave per stage ----
        const short* Bp = Bsrc + (size_t)n0 * DMODEL;
        stage32_128(Asrc, 0,  (char*)As[0], wid, lane);
        stage32_128(Bp,   0,  (char*)Bs[0], wid, lane);
        stage32_128(Asrc, 32, (char*)As[1], wid, lane);
        stage32_128(Bp,   32, (char*)Bs[1], wid, lane);
        for (int it = 0; it < 32; ++it) {
            if (it < 31) asm volatile("s_waitcnt vmcnt(4)" ::: "memory");
            else         asm volatile("s_waitcnt vmcnt(0)" ::: "memory");
            __builtin_amdgcn_s_barrier();
            __builtin_amdgcn_sched_barrier(0);
            if (it + 2 < 32) {
                const int nb = (it + 2) % 3;
                stage32_128(Asrc, (it + 2) * 32, (char*)As[nb], wid, lane);
                stage32_128(Bp,   (it + 2) * 32, (char*)Bs[nb], wid, lane);
            }
            const short* Ab = As[it % 3];
            const short* Bb = Bs[it % 3];
            bf16x8 a[4], b[4];
#pragma unroll
            for (int i = 0; i < 4; i++)
                a[i] = *(const bf16x8*)&Ab[(wm * 64 + i * 16 + l15) * 32 + ch];
#pragma unroll
            for (int j = 0; j < 4; j++)
                b[j] = *(const bf16x8*)&Bb[(wn * 64 + j * 16 + l15) * 32 + ch];
            __builtin_amdgcn_s_setprio(1);
#pragma unroll
            for (int i = 0; i < 4; i++)
#pragma unroll
                for (int j = 0; j < 4; j++)
                    acc[i][j] = __builtin_amdgcn_mfma_f32_16x16x32_bf16(a[i], b[j], acc[i][j], 0, 0, 0);
            __builtin_amdgcn_s_setprio(0);
        }
    } else {
        // ---- drain-style dbuf (buffers 0/1), B = v fp32 reg-staged ----
        const int brow = t >> 1, bh2 = t & 1;
        auto writeBrow = [&](int buf, const f32x4* br) {
#pragma unroll
            for (int j = 0; j < 2; j++) {
                f32x4 x = br[2 * j], y = br[2 * j + 1];
                bf16x8 w;
                w[0]=f2bf(x[0]); w[1]=f2bf(x[1]); w[2]=f2bf(x[2]); w[3]=f2bf(x[3]);
                w[4]=f2bf(y[0]); w[5]=f2bf(y[1]); w[6]=f2bf(y[2]); w[7]=f2bf(y[3]);
                const int cp = (bh2 * 2 + j) ^ ((brow >> 1) & 3);
                *(bf16x8*)&Bs[buf][brow * 32 + cp * 8] = w;
            }
        };

        stage32_128(Asrc, 0, (char*)As[0], wid, lane);
        {
            f32x4 br[4];
            const f32x4* p = (const f32x4*)&vf[(size_t)(n0 + brow) * DMODEL + bh2 * 16];
#pragma unroll
            for (int j = 0; j < 4; j++) br[j] = p[j];
            writeBrow(0, br);
        }
        __syncthreads();

        int cur = 0;
        for (int kt = 0; kt < DMODEL; kt += 32) {
            const int nxt = cur ^ 1;
            const bool pre = (kt + 32 < DMODEL);
            f32x4 br[4];
            if (pre) {
                stage32_128(Asrc, kt + 32, (char*)As[nxt], wid, lane);
                const f32x4* p = (const f32x4*)&vf[(size_t)(n0 + brow) * DMODEL + kt + 32 + bh2 * 16];
#pragma unroll
                for (int j = 0; j < 4; j++) br[j] = p[j];
            }

            bf16x8 a[4], b[4];
#pragma unroll
            for (int i = 0; i < 4; i++)
                a[i] = *(const bf16x8*)&As[cur][(wm * 64 + i * 16 + l15) * 32 + ch];
#pragma unroll
            for (int j = 0; j < 4; j++)
                b[j] = *(const bf16x8*)&Bs[cur][(wn * 64 + j * 16 + l15) * 32 + ch];
#pragma unroll
            for (int i = 0; i < 4; i++)
#pragma unroll
                for (int j = 0; j < 4; j++)
                    acc[i][j] = __builtin_amdgcn_mfma_f32_16x16x32_bf16(a[i], b[j], acc[i][j], 0, 0, 0);

            if (pre) writeBrow(nxt, br);
            __syncthreads();
            cur = nxt;
        }
    }

#pragma unroll
    for (int i = 0; i < 4; i++) {
        const int mbase = m0 + wm * 64 + i * 16 + l4 * 4;
#pragma unroll
        for (int j = 0; j < 4; j++) {
            const int n = n0 + wn * 64 + j * 16 + l15;
#pragma unroll
            for (int r = 0; r < 4; r++) {
                const int m = mbase + r;
                if (op < 2) {
                    float y = (acc[i][j][r] + bias[n]) * scale;
                    const int b_ = m >> 11, s_ = m & 2047;
                    const int h_ = n >> 6,  d_ = n & 63;
                    C[((((size_t)b_ * H + h_) * SS + s_) << 6) + d_] = f2bf(y);
                } else {
                    C[(size_t)m * ROWS + n] = f2bf(acc[i][j][r] + bias[m]);
                }
            }
        }
    }
}

// O-projection: OW[4096][1024] fp32 = Oc @ Wo^T + bo. 64x128 tiles, BK=32,
// counted-vmcnt 2-ahead triple-buffer, 512 blocks XCD-chunked.
__global__ __launch_bounds__(256, 3)
void oproj(const short* __restrict__ Oc, const short* __restrict__ Wo,
           const float* __restrict__ bo, float* __restrict__ out)
{
    __shared__ short As[3][64 * 32];
    __shared__ short Bs[3][128 * 32];

    const int fbid = blockIdx.x;
    const int vbid = (fbid & 7) * 64 + (fbid >> 3);
    const int m0   = (vbid >> 3) * 64;
    const int n0   = (vbid & 7) * 128;
    const int t    = threadIdx.x;
    const int lane = t & 63;
    const int wid  = t >> 6;
    const int wm   = wid >> 1;
    const int wn   = wid & 1;
    const int l15  = lane & 15;
    const int l4   = lane >> 4;
    const int ch   = (l4 ^ ((l15 >> 1) & 3)) * 8;

    f32x4 acc[2][4];
#pragma unroll
    for (int i = 0; i < 2; i++)
#pragma unroll
        for (int j = 0; j < 4; j++) acc[i][j] = (f32x4)0.0f;

    const short* Ap = Oc + (size_t)m0 * DMODEL;
    const short* Bp = Wo + (size_t)n0 * DMODEL;

    stage32_64 (Ap, 0,  (char*)As[0], wid, lane);
    stage32_128(Bp, 0,  (char*)Bs[0], wid, lane);
    stage32_64 (Ap, 32, (char*)As[1], wid, lane);
    stage32_128(Bp, 32, (char*)Bs[1], wid, lane);

    for (int it = 0; it < 32; ++it) {
        if (it < 31) asm volatile("s_waitcnt vmcnt(3)" ::: "memory");
        else         asm volatile("s_waitcnt vmcnt(0)" ::: "memory");
        __builtin_amdgcn_s_barrier();
        __builtin_amdgcn_sched_barrier(0);
        if (it + 2 < 32) {
            const int nb = (it + 2) % 3;
            stage32_64 (Ap, (it + 2) * 32, (char*)As[nb], wid, lane);
            stage32_128(Bp, (it + 2) * 32, (char*)Bs[nb], wid, lane);
        }
        const short* Ab = As[it % 3];
        const short* Bb = Bs[it % 3];
        bf16x8 a[2], b[4];
#pragma unroll
        for (int i = 0; i < 2; i++)
            a[i] = *(const bf16x8*)&Ab[(wm * 32 + i * 16 + l15) * 32 + ch];
#pragma unroll
        for (int j = 0; j < 4; j++)
            b[j] = *(const bf16x8*)&Bb[(wn * 64 + j * 16 + l15) * 32 + ch];
        __builtin_amdgcn_s_setprio(1);
#pragma unroll
        for (int i = 0; i < 2; i++)
#pragma unroll
            for (int j = 0; j < 4; j++)
                acc[i][j] = __builtin_amdgcn_mfma_f32_16x16x32_bf16(a[i], b[j], acc[i][j], 0, 0, 0);
        __builtin_amdgcn_s_setprio(0);
    }

#pragma unroll
    for (int i = 0; i < 2; i++) {
        const int mbase = m0 + wm * 32 + i * 16 + l4 * 4;
#pragma unroll
        for (int j = 0; j < 4; j++) {
            const int n = n0 + wn * 64 + j * 16 + l15;
#pragma unroll
            for (int r = 0; r < 4; r++)
                out[(size_t)(mbase + r) * DMODEL + n] = acc[i][j][r] + bo[n];
        }
    }
}

// Flash attention, causal, paired q-tiles, double-buffered K/V, 1 barrier/iter.
// SWAPPED QK^T: S^T = mfma(K,Q) -> each lane owns one q-row (q=l15), 16 kv regs.
__global__ __launch_bounds__(256, 2)
void attn_fwd(const short* __restrict__ Qh, const short* __restrict__ Kh,
              const short* __restrict__ Vt, short* __restrict__ Oc)
{
    __shared__ short Ks[2][64][64];
    __shared__ short Vs[2][64][64];
    __shared__ short Ps[4][16][72];   // [wave][q_local][kv]

    const int t    = threadIdx.x;
    const int lane = t & 63;
    const int wid  = t >> 6;
    const int fbid = blockIdx.x;
    const int vbid = (fbid & 7) * 64 + (fbid >> 3);
    const int bh   = vbid >> 4;
    const int qp   = vbid & 15;
    const int b    = bh >> 4;
    const int h    = bh & 15;
    const int l15  = lane & 15;
    const int l4   = lane >> 4;

    const int srow = wid * 8 + (lane >> 3);
    const int sch  = lane & 7;
    const int ldsoff = wid * 1024;

    auto stage = [&](int buf, int kvt) {
#pragma unroll
        for (int i = 0; i < 2; i++) {
            const int row = i * 32 + srow;
            const int chg = sch ^ (row & 7);
            gload_lds16(&Kh[((size_t)bh * SS + kvt * 64 + row) * 64 + chg * 8],
                        (char*)Ks + buf * 8192 + ldsoff + i * 4096);
            gload_lds16(&Vt[((size_t)(h * 64 + row)) * ROWS + b * SS + kvt * 64 + chg * 8],
                        (char*)Vs + buf * 8192 + ldsoff + i * 4096);
        }
    };

    for (int half = 0; half < 2; ++half) {
        const int qt = half ? (31 - qp) : qp;

        bf16x8 qa[2];
        {
            const int qrow = qt * 64 + wid * 16 + l15;
            const size_t base = ((size_t)bh * SS + qrow) * 64;
            qa[0] = *(const bf16x8*)&Qh[base + l4 * 8];
            qa[1] = *(const bf16x8*)&Qh[base + 32 + l4 * 8];
        }

        f32x4 accO[4];
#pragma unroll
        for (int i = 0; i < 4; i++) accO[i] = (f32x4)0.f;
        float mrun = -1e30f, lrun = 0.f;

        stage(0, 0);
        __syncthreads();

        int cur = 0;
        for (int kvt = 0; kvt <= qt; ++kvt) {
            if (kvt < qt) stage(cur ^ 1, kvt + 1);

            f32x4 sc[4];
#pragma unroll
            for (int i = 0; i < 4; i++) sc[i] = (f32x4)0.f;
            __builtin_amdgcn_s_setprio(1);
#pragma unroll
            for (int kk = 0; kk < 2; kk++) {
#pragma unroll
                for (int fn = 0; fn < 4; fn++) {
                    const int chk = (kk * 4 + l4) ^ (l15 & 7);
                    bf16x8 kb = *(const bf16x8*)&Ks[cur][fn * 16 + l15][chk * 8];
                    sc[fn] = __builtin_amdgcn_mfma_f32_16x16x32_bf16(kb, qa[kk], sc[fn], 0, 0, 0);
                }
            }
            __builtin_amdgcn_s_setprio(0);

            if (kvt == qt) {
                const int qg = wid * 16 + l15;
#pragma unroll
                for (int fn = 0; fn < 4; fn++)
#pragma unroll
                    for (int r = 0; r < 4; r++)
                        if (fn * 16 + l4 * 4 + r > qg) sc[fn][r] = -1e30f;
            }

            float pmax = sc[0][0];
#pragma unroll
            for (int fn = 0; fn < 4; fn++)
#pragma unroll
                for (int r = 0; r < 4; r++)
                    pmax = fmaxf(pmax, sc[fn][r]);
            pmax = fmaxf(pmax, __shfl_xor(pmax, 16));
            pmax = fmaxf(pmax, __shfl_xor(pmax, 32));

            if (__any(pmax > mrun + 8.0f)) {
                const float mn = fmaxf(mrun, pmax);
                const float es = __expf(mrun - mn);
                mrun = mn;
                lrun *= es;
                float esr[4];
#pragma unroll
                for (int r = 0; r < 4; r++) esr[r] = __shfl(es, l4 * 4 + r);
#pragma unroll
                for (int fd = 0; fd < 4; fd++)
#pragma unroll
                    for (int r = 0; r < 4; r++) accO[fd][r] *= esr[r];
            }

            float rs = 0.f;
#pragma unroll
            for (int fn = 0; fn < 4; fn++)
#pragma unroll
                for (int r = 0; r < 4; r++) {
                    const float p = __expf(sc[fn][r] - mrun);
                    sc[fn][r] = p;
                    rs += p;
                }
            rs += __shfl_xor(rs, 16);
            rs += __shfl_xor(rs, 32);
            lrun += rs;

#pragma unroll
            for (int fn = 0; fn < 4; fn++) {
                short4v w4;
                w4[0] = f2bf(sc[fn][0]); w4[1] = f2bf(sc[fn][1]);
                w4[2] = f2bf(sc[fn][2]); w4[3] = f2bf(sc[fn][3]);
                *(short4v*)&Ps[wid][l15][fn * 16 + l4 * 4] = w4;
            }

            __builtin_amdgcn_s_setprio(1);
#pragma unroll
            for (int kk = 0; kk < 2; kk++) {
                bf16x8 pa = *(const bf16x8*)&Ps[wid][l15][kk * 32 + l4 * 8];
#pragma unroll
                for (int fd = 0; fd < 4; fd++) {
                    const int chk = (kk * 4 + l4) ^ (l15 & 7);
                    bf16x8 vb = *(const bf16x8*)&Vs[cur][fd * 16 + l15][chk * 8];
                    accO[fd] = __builtin_amdgcn_mfma_f32_16x16x32_bf16(pa, vb, accO[fd], 0, 0, 0);
                }
            }
            __builtin_amdgcn_s_setprio(0);

            __syncthreads();
            cur ^= 1;
        }

        float linv[4];
#pragma unroll
        for (int r = 0; r < 4; r++) linv[r] = 1.0f / __shfl(lrun, l4 * 4 + r);
#pragma unroll
        for (int fd = 0; fd < 4; fd++)
#pragma unroll
            for (int r = 0; r < 4; r++) {
                const int q = qt * 64 + wid * 16 + l4 * 4 + r;
                const size_t idx = ((size_t)b * SS + q) * DMODEL + h * 64 + fd * 16 + l15;
                Oc[idx] = f2bf(accO[fd][r] * linv[r]);
            }
    }
}

extern "C" void kernel_launch(void* const* d_in, const int* in_sizes, int n_in,
                              void* d_out, int out_size, void* d_ws, size_t ws_size,
                              hipStream_t stream) {
    const float* q   = (const float*)d_in[0];
    const float* k   = (const float*)d_in[1];
    const float* v   = (const float*)d_in[2];
    const float* w_q = (const float*)d_in[4];
    const float* b_q = (const float*)d_in[5];
    const float* w_k = (const float*)d_in[6];
    const float* b_k = (const float*)d_in[7];
    const float* w_v = (const float*)d_in[8];
    const float* b_v = (const float*)d_in[9];
    const float* w_o = (const float*)d_in[10];
    const float* b_o = (const float*)d_in[11];

    const size_t T = (size_t)ROWS * DMODEL;   // 4M elements
    const size_t W = (size_t)DMODEL * DMODEL; // 1M elements
    short* Qh  = (short*)d_ws;
    short* Kh  = Qh + T;
    short* Vt  = Kh + T;
    short* Wb  = Vt + T;
    short* Wq16 = Wb, *Wk16 = Wb + W, *Wv16 = Wb + 2 * W, *Wo16 = Wb + 3 * W;
    short* Qb  = (short*)d_out;
    short* Kb  = Qb + T;
    short* Oc  = (short*)d_out;
    float* OW  = (float*)d_ws;                // oproj fp32 result (over dead Qh/Kh)

    dim3 blk(256);
    cvt<<<dim3(6144), blk, 0, stream>>>(q, k, w_q, w_k, w_v, w_o, Qb, Kb, Wb);
    qkv_proj<<<dim3(768), blk, 0, stream>>>(Qb, Kb, v, Wq16, Wk16, Wv16,
                                            b_q, b_k, b_v, Qh, Kh, Vt);
    attn_fwd<<<dim3(512), blk, 0, stream>>>(Qh, Kh, Vt, Oc);
    oproj<<<dim3(512), blk, 0, stream>>>(Oc, Wo16, b_o, OW);
    hipMemcpyAsync(d_out, d_ws, (size_t)ROWS * DMODEL * sizeof(float),
                   hipMemcpyDeviceToDevice, stream);
}